// Round 9
// baseline (387.310 us; speedup 1.0000x reference)
//
#include <hip/hip_runtime.h>
#include <cstdint>

#define Bc  2
#define Sc  2048
#define Dc  1024
#define Ec  1024
#define Hc  16
#define HDc 64
#define TTc (Bc*Sc)
#define TILE_R 128
#define NTILES 36
#define EPSc 1e-5f
#define LOG2E 1.44269504f
#define C2    (0.125f*LOG2E)

typedef unsigned short u16;
using bf8   = __attribute__((ext_vector_type(8))) short;
using f32x4 = __attribute__((ext_vector_type(4))) float;
#define MFMA(a,b,c) __builtin_amdgcn_mfma_f32_16x16x32_bf16(a,b,c,0,0,0)

static __device__ __forceinline__ u16 f2b(float f){
    return (u16)((__float_as_uint(f) + 0x8000u) >> 16);
}
static __device__ __forceinline__ float b2f(u16 s){
    return __uint_as_float(((unsigned)s) << 16);
}
// raw v_exp_f32 (2^x): inputs here are <= ~8; underflow flushes to 0 which is
// exactly the wanted semantics. Avoids OCML's multi-instruction wrapper.
static __device__ __forceinline__ float ex2(float x){
    return __builtin_amdgcn_exp2f(x);
}
// pack two f32 -> one dword of 2 bf16 (low = a, high = b), single VALU op
static __device__ __forceinline__ unsigned cvtpk(float a, float b){
    unsigned r;
    asm("v_cvt_pk_bf16_f32 %0, %1, %2" : "=v"(r) : "v"(a), "v"(b));
    return r;
}
union bfpack { unsigned u[4]; bf8 v; };
// 3-input max; clang fuses to v_max3_f32
static __device__ __forceinline__ float max3f(float a, float b, float c){
    return fmaxf(fmaxf(a, b), c);
}
// XOR-swizzled LDS addressing: tiles are [R][64] u16, 8-u16 (16B) groups,
// group index col8 swizzled by row&7 -> fragment ds_read_b128 is
// bank-conflict-free.
static __device__ __forceinline__ u16* swz(u16* base, int row, int col8){
    return base + row*64 + ((col8 ^ (row & 7)) << 3);
}
static __device__ __forceinline__ const u16* swzc(const u16* base, int row, int col8){
    return base + row*64 + ((col8 ^ (row & 7)) << 3);
}
// async global->LDS, 16B per lane. LDS dest = wave-uniform base + lane*16
// (linear); the swizzle is applied by inverse-permuting the per-lane global
// source address (rule: linear dest + inv-swz source + swz read).
typedef const __attribute__((address_space(1))) void* gp1;
typedef __attribute__((address_space(3))) void* lp3;
static __device__ __forceinline__ void gl16(const void* g, void* l){
    __builtin_amdgcn_global_load_lds((gp1)g, (lp3)l, 16, 0, 0);
}
// inverse of the k_flash pi row permutation (pi: pr4=g2, pr3=g4, pr2=g3)
static __device__ __forceinline__ int pinv(int lr){
    return (lr & 0x23) | ((lr & 0x10) >> 2) | ((lr & 0x0C) << 1);
}

// ---------------------------------------------------------------------------
// 1. modality-sorted token permutation, 128-padded segments per (b,m).
//    Also zeroes the 4KB zbuf used by gload_lds staging for padding rows.
// ---------------------------------------------------------------------------
__global__ void k_perm(const int* __restrict__ mod, int* __restrict__ perm,
                       int* __restrict__ tmeta, u16* __restrict__ zbuf)
{
    __shared__ int cnt[4], segstart[4];
    int t = threadIdx.x;
    for (int i = t; i < 2048; i += 256) zbuf[i] = 0;
    if (t < 4) cnt[t] = 0;
    __syncthreads();
    for (int i = t; i < TTc; i += 256){
        int b = i >> 11; int m = mod[i];
        atomicAdd(&cnt[b*2+m], 1);
    }
    __syncthreads();
    if (t == 0){
        int off = 0;
        for (int i = 0; i < 4; i++){
            segstart[i] = off;
            int pad = ((cnt[i] + TILE_R - 1)/TILE_R)*TILE_R;
            for (int tt = off/TILE_R; tt < (off+pad)/TILE_R; tt++) tmeta[tt] = i;
            off += pad;
        }
        for (int tt = off/TILE_R; tt < NTILES; tt++) tmeta[tt] = -1;
    }
    __syncthreads();
    if (t < 4) cnt[t] = 0;
    for (int i = t; i < NTILES*TILE_R; i += 256) perm[i] = -1;
    __syncthreads();
    for (int i = t; i < TTc; i += 256){
        int b = i >> 11, s = i & 2047; int m = mod[i];
        int r = atomicAdd(&cnt[b*2+m], 1);
        perm[segstart[b*2+m] + r] = s;
    }
}

// ---------------------------------------------------------------------------
// 2. fused fp32->bf16 conversion: x (plain) + mask (scaled by LOG2E).
//    grid 8192: blocks [0,4096) -> x, [4096,8192) -> mask.
// ---------------------------------------------------------------------------
__global__ __launch_bounds__(256) void k_prep(
    const float* __restrict__ x, const float* __restrict__ mask,
    u16* __restrict__ xb, u16* __restrict__ maskb)
{
    int bid = blockIdx.x;
    if (bid < 4096){
        int i = (bid*256 + threadIdx.x)*4;
        float4 v = *(const float4*)&x[i];
        ushort4 o;
        o.x = f2b(v.x); o.y = f2b(v.y); o.z = f2b(v.z); o.w = f2b(v.w);
        *(ushort4*)&xb[i] = o;
    } else {
        int i = ((bid-4096)*256 + threadIdx.x)*4;
        float4 v = *(const float4*)&mask[i];
        ushort4 o;
        o.x = f2b(v.x*LOG2E); o.y = f2b(v.y*LOG2E);
        o.z = f2b(v.z*LOG2E); o.w = f2b(v.w*LOG2E);
        *(ushort4*)&maskb[i] = o;
    }
}

// ---------------------------------------------------------------------------
// 3. transpose+convert all four weights in one launch; grid (32,32,8)
// ---------------------------------------------------------------------------
__global__ __launch_bounds__(256) void k_tcvt(
    const float* __restrict__ s0, const float* __restrict__ s1,
    const float* __restrict__ s2, const float* __restrict__ s3,
    u16* __restrict__ d0, u16* __restrict__ d1,
    u16* __restrict__ d2, u16* __restrict__ d3)
{
    int wsel = blockIdx.z >> 1, m = blockIdx.z & 1;
    const float* src = (wsel==0?s0:wsel==1?s1:wsel==2?s2:s3) + (size_t)m*1048576;
    u16*       dst = (wsel==0?d0:wsel==1?d1:wsel==2?d2:d3) + (size_t)m*1048576;
    __shared__ float sh[32][33];
    int t = threadIdx.x;
    int i0 = blockIdx.x*32, j0 = blockIdx.y*32;
    {
        int i = t >> 3, j4 = (t & 7)*4;
        *(float4*)&sh[i][j4] = *(const float4*)&src[(size_t)(i0+i)*1024 + j0 + j4];
    }
    __syncthreads();
    {
        int j = t >> 3, i4 = (t & 7)*4;
        ushort4 o;
        o.x = f2b(sh[i4+0][j]); o.y = f2b(sh[i4+1][j]);
        o.z = f2b(sh[i4+2][j]); o.w = f2b(sh[i4+3][j]);
        *(ushort4*)&dst[(size_t)(j0+j)*1024 + i0 + i4] = o;
    }
}

// ---------------------------------------------------------------------------
// 4. QKV projection, MFMA, fused per-head RMSNorm for Q and K.
//    grid (8, NTILES, 3). LDS tiles XOR-swizzled [128][64], staged via
//    global_load_lds (linear dest, inverse-swizzled per-lane source).
//    Q folded with C2 = 0.125*log2e.
// ---------------------------------------------------------------------------
__global__ __launch_bounds__(256) void k_qkv(
    const u16* __restrict__ xb, const u16* __restrict__ wqT,
    const u16* __restrict__ wkT, const u16* __restrict__ wvT,
    const int* __restrict__ perm, const int* __restrict__ tmeta,
    const float* __restrict__ qnw, const float* __restrict__ knw,
    const u16* __restrict__ zbuf,
    u16* __restrict__ qb, u16* __restrict__ kb, u16* __restrict__ vb)
{
    int meta = tmeta[blockIdx.y];
    if (meta < 0) return;
    int b = meta >> 1, m = meta & 1;
    const u16* W = (blockIdx.z==0 ? wqT : (blockIdx.z==1 ? wkT : wvT)) + (size_t)m*Ec*Dc;
    u16* outp    = (blockIdx.z==0 ? qb  : (blockIdx.z==1 ? kb  : vb));
    int c0 = blockIdx.x*128;
    int t = threadIdx.x, lane = t & 63, wv_ = t >> 6;
    int quad = lane >> 4, lc = lane & 15;

    __shared__ u16 at[128*64];
    __shared__ u16 bt[128*64];
    __shared__ int sperm[128];
    if (t < 128) sperm[t] = perm[blockIdx.y*128 + t];
    f32x4 acc[2][8];
    #pragma unroll
    for (int i=0;i<2;i++)
        #pragma unroll
        for (int j=0;j<8;j++) acc[i][j] = (f32x4){0.f,0.f,0.f,0.f};
    __syncthreads();

    // staging sources: wave w instr i lane l covers LDS row w*32+i*8+(l>>3),
    // stored group l&7 -> true col8 = (l&7)^(l>>3) (row&7 == l>>3).
    int colsw = ((lane & 7) ^ (lane >> 3)) << 3;
    const u16* ab[4]; const u16* bb[4];
    #pragma unroll
    for (int i = 0; i < 4; i++){
        int row = wv_*32 + i*8 + (lane >> 3);
        int s_ = sperm[row];
        ab[i] = (s_ >= 0) ? (xb + ((size_t)(b*Sc + s_))*Dc + colsw) : zbuf;
        bb[i] = W + (size_t)(c0 + row)*Dc + colsw;
    }

    for (int d0 = 0; d0 < Dc; d0 += 64){
        #pragma unroll
        for (int i = 0; i < 4; i++){
            gl16(ab[i] + d0, &at[(wv_*4 + i)*512]);
            gl16(bb[i] + d0, &bt[(wv_*4 + i)*512]);
        }
        __syncthreads();
        #pragma unroll
        for (int ks = 0; ks < 2; ks++){
            bf8 a0 = *(const bf8*)swzc(at, wv_*32 + lc,      ks*4 + quad);
            bf8 a1 = *(const bf8*)swzc(at, wv_*32 + 16 + lc, ks*4 + quad);
            #pragma unroll
            for (int nb = 0; nb < 8; nb++){
                bf8 bb2 = *(const bf8*)swzc(bt, nb*16 + lc, ks*4 + quad);
                acc[0][nb] = MFMA(a0, bb2, acc[0][nb]);
                acc[1][nb] = MFMA(a1, bb2, acc[1][nb]);
            }
        }
        __syncthreads();
    }

    if (blockIdx.z < 2){
        const float* nw = (blockIdx.z==0 ? qnw : knw) + m*HDc;
        float cs = (blockIdx.z==0) ? C2 : 1.f;   // fold score scale into Q
        float w0 = nw[lc]*cs, w1 = nw[16+lc]*cs, w2 = nw[32+lc]*cs, w3 = nw[48+lc]*cs;
        #pragma unroll
        for (int mb = 0; mb < 2; mb++){
            #pragma unroll
            for (int r = 0; r < 4; r++){
                #pragma unroll
                for (int g = 0; g < 2; g++){
                    float ss = 0.f;
                    #pragma unroll
                    for (int j = 0; j < 4; j++){
                        float v2 = acc[mb][g*4+j][r];
                        ss += v2*v2;
                    }
                    ss += __shfl_xor(ss, 1, 64);
                    ss += __shfl_xor(ss, 2, 64);
                    ss += __shfl_xor(ss, 4, 64);
                    ss += __shfl_xor(ss, 8, 64);
                    float rs = rsqrtf(ss*(1.f/64.f) + EPSc);
                    acc[mb][g*4+0][r] *= rs*w0;
                    acc[mb][g*4+1][r] *= rs*w1;
                    acc[mb][g*4+2][r] *= rs*w2;
                    acc[mb][g*4+3][r] *= rs*w3;
                }
            }
        }
    }

    int h0 = c0 >> 6;
    #pragma unroll
    for (int mb = 0; mb < 2; mb++){
        #pragma unroll
        for (int r = 0; r < 4; r++){
            int row = wv_*32 + mb*16 + quad*4 + r;
            int s_ = sperm[row];
            if (s_ < 0) continue;
            #pragma unroll
            for (int nb = 0; nb < 8; nb++){
                int col = nb*16 + lc;
                int h = h0 + (col >> 6), hd = col & 63;
                outp[(((size_t)(b*Hc + h))*Sc + s_)*HDc + hd] = f2b(acc[mb][nb][r]);
            }
        }
    }
}

// ---------------------------------------------------------------------------
// 6. V transpose via LDS tiles: vb [BH][S][HD] -> vtb [BH][HD][S]
// ---------------------------------------------------------------------------
__global__ __launch_bounds__(256) void k_vt(const u16* __restrict__ vb,
                                            u16* __restrict__ vtb)
{
    __shared__ u16 sh[64][72];
    int t = threadIdx.x;
    int s0 = blockIdx.x*64, bh = blockIdx.y;
    {
        int rr = t >> 2, cc = (t & 3)*16;
        const u16* src = vb + ((size_t)bh*Sc + s0 + rr)*HDc + cc;
        *(uint4*)&sh[rr][cc]   = *(const uint4*)(src);
        *(uint4*)&sh[rr][cc+8] = *(const uint4*)(src+8);
    }
    __syncthreads();
    {
        int hd = t >> 2, sc = (t & 3)*16;
        u16 tmp[16];
        #pragma unroll
        for (int j = 0; j < 16; j++) tmp[j] = sh[sc+j][hd];
        u16* dst = vtb + ((size_t)bh*HDc + hd)*Sc + s0 + sc;
        *(uint4*)(dst)   = *(const uint4*)&tmp[0];
        *(uint4*)(dst+8) = *(const uint4*)&tmp[8];
    }
}

// ---------------------------------------------------------------------------
// 9. flash PV with ONLINE softmax + defer-max (THR=8), split-K x2:
//    grid (32, 16, 4): z = b*2 + half.
//    2-PHASE DOUBLE-BUFFERED PIPELINE (T3 minimum recipe): stage tile t+1
//    (gl16 K/V + mask regs) at loop top, compute tile t, ONE barrier/tile.
//    Staging latency hides under compute; barriers halved.
//    Swapped QK^T + pi-permuted K keeps P in registers in exact PV A-frag
//    layout. Row-sum l via MFMA ones-operand (racc rows == oacc rows).
//    max3 tree, cvt_pk pack, native v_exp_f32, defer-max.
// ---------------------------------------------------------------------------
__global__ __launch_bounds__(256) void k_flash(
    const u16* __restrict__ qb, const u16* __restrict__ kb,
    const u16* __restrict__ vtb, const u16* __restrict__ maskb,
    float* __restrict__ pm, float* __restrict__ pl,
    u16* __restrict__ c0, u16* __restrict__ c1)
{
    int qs0 = blockIdx.x*64, h = blockIdx.y;
    int b = blockIdx.z >> 1, half = blockIdx.z & 1;
    u16* ctxh = half ? c1 : c0;
    int t = threadIdx.x, lane = t & 63, wv_ = t >> 6;
    int quad = lane >> 4, lc = lane & 15;
    __shared__ u16 kt[2][64*64];
    __shared__ u16 vt[2][64*64];
    const u16* qp  = qb  + ((size_t)(b*Hc+h))*Sc*HDc;
    const u16* kp  = kb  + ((size_t)(b*Hc+h))*Sc*HDc;
    const u16* vtp = vtb + ((size_t)(b*Hc+h))*HDc*Sc;
    const u16* mq  = maskb + (size_t)(qs0 + wv_*16 + lc)*Sc;  // this lane's q-row
    bf8 aq[2];
    #pragma unroll
    for (int ks = 0; ks < 2; ks++)
        aq[ks] = *(const bf8*)(qp + (size_t)(qs0 + wv_*16 + lc)*HDc + ks*32 + quad*8);
    // all-ones B fragment for MFMA row sums
    bfpack onep; onep.u[0] = onep.u[1] = onep.u[2] = onep.u[3] = 0x3F803F80u;
    bf8 ones = onep.v;
    // online stats: rm per-lane for q-row lc; l via racc (rows quad*4+r)
    float rm = -1.0e30f;
    f32x4 racc = (f32x4){0.f,0.f,0.f,0.f};
    f32x4 oacc[4];
    #pragma unroll
    for (int j=0;j<4;j++) oacc[j] = (f32x4){0.f,0.f,0.f,0.f};

    // gl16 staging geometry (per wave: rows w*16..w*16+15 of each tile)
    int lsub = lane >> 3;
    int colsw = ((lane & 7) ^ lsub) << 3;
    int lrA = wv_*16 + lsub, lrB = wv_*16 + 8 + lsub;
    const u16* kg0 = kp + (size_t)pinv(lrA)*HDc + colsw;
    const u16* kg1 = kp + (size_t)pinv(lrB)*HDc + colsw;
    const u16* vg0 = vtp + (size_t)lrA*Sc + colsw;
    const u16* vg1 = vtp + (size_t)lrB*Sc + colsw;
    int kdo0 = (wv_*16 + 0)*64, kdo1 = (wv_*16 + 8)*64;

    int kc0 = half*1024, kcend = kc0 + 1024;
    // prologue: stage tile 0 into buffer 0, prefetch its mask
    gl16(kg0 + (size_t)kc0*HDc, &kt[0][kdo0]);
    gl16(kg1 + (size_t)kc0*HDc, &kt[0][kdo1]);
    gl16(vg0 + kc0, &vt[0][kdo0]);
    gl16(vg1 + kc0, &vt[0][kdo1]);
    ushort4 mv[2][2];
    #pragma unroll
    for (int a1 = 0; a1 < 2; a1++)
        #pragma unroll
        for (int b1 = 0; b1 < 2; b1++)
            mv[a1][b1] = *(const ushort4*)(mq + kc0 + a1*32 + quad*8 + b1*4);
    __syncthreads();   // drains prologue staging -> buffer 0 ready

    int cur = 0;
    for (int kc = kc0; kc < kcend; kc += 64){
        // stage NEXT tile into the shadow buffer (clamped on last iter;
        // redundant loads land in the unused buffer, drained by last barrier)
        int nxt = (kc + 64 < kcend) ? kc + 64 : kc;
        gl16(kg0 + (size_t)nxt*HDc, &kt[cur^1][kdo0]);
        gl16(kg1 + (size_t)nxt*HDc, &kt[cur^1][kdo1]);
        gl16(vg0 + nxt, &vt[cur^1][kdo0]);
        gl16(vg1 + nxt, &vt[cur^1][kdo1]);
        ushort4 mvn[2][2];
        #pragma unroll
        for (int a1 = 0; a1 < 2; a1++)
            #pragma unroll
            for (int b1 = 0; b1 < 2; b1++)
                mvn[a1][b1] = *(const ushort4*)(mq + nxt + a1*32 + quad*8 + b1*4);

        const u16* ktc = kt[cur];
        const u16* vtc = vt[cur];
        // S^T = K * Q^T (Q pre-scaled by C2)
        f32x4 acc[4];
        #pragma unroll
        for (int j=0;j<4;j++) acc[j] = (f32x4){0.f,0.f,0.f,0.f};
        #pragma unroll
        for (int ks = 0; ks < 2; ks++){
            #pragma unroll
            for (int nb = 0; nb < 4; nb++){
                bf8 ak = *(const bf8*)swzc(ktc, nb*16 + lc, ks*4 + quad);
                acc[nb] = MFMA(ak, aq[ks], acc[nb]);
            }
        }
        // scores + mask; per-lane max via max3 tree
        float svv[4][4];
        #pragma unroll
        for (int a1 = 0; a1 < 2; a1++){
            #pragma unroll
            for (int b1 = 0; b1 < 2; b1++){
                int nb = 2*a1 + b1;
                #pragma unroll
                for (int r = 0; r < 4; r++){
                    u16 mraw = (r==0?mv[a1][b1].x:r==1?mv[a1][b1].y:
                                r==2?mv[a1][b1].z:mv[a1][b1].w);
                    svv[nb][r] = acc[nb][r] + b2f(mraw);
                }
            }
        }
        float m0_ = max3f(svv[0][0], svv[0][1], svv[0][2]);
        float m1_ = max3f(svv[0][3], svv[1][0], svv[1][1]);
        float m2_ = max3f(svv[1][2], svv[1][3], svv[2][0]);
        float m3_ = max3f(svv[2][1], svv[2][2], svv[2][3]);
        float m4_ = max3f(svv[3][0], svv[3][1], svv[3][2]);
        float mxl = fmaxf(max3f(m0_, m1_, m2_), max3f(m3_, m4_, svv[3][3]));
        // defer-max: only reduce/rescale when some lane grew past rm + 8
        if (__any(mxl > rm + 8.f)){
            float mx = fmaxf(mxl, __shfl_xor(mxl, 16, 64));
            mx = fmaxf(mx, __shfl_xor(mx, 32, 64));
            float nm = fmaxf(rm, mx);
            float fac = ex2(rm - nm);
            rm = nm;
            float f0 = __shfl(fac, quad*4+0, 64);
            float f1 = __shfl(fac, quad*4+1, 64);
            float f2 = __shfl(fac, quad*4+2, 64);
            float f3 = __shfl(fac, quad*4+3, 64);
            racc[0] *= f0; racc[1] *= f1; racc[2] *= f2; racc[3] *= f3;
            #pragma unroll
            for (int nb = 0; nb < 4; nb++){
                oacc[nb][0] *= f0; oacc[nb][1] *= f1;
                oacc[nb][2] *= f2; oacc[nb][3] *= f3;
            }
        }
        // P (bounded by 2^8) packed via cvt_pk straight into PV A-fragments;
        // row sums accumulated on the matrix pipe via the ones fragment.
        #pragma unroll
        for (int a1 = 0; a1 < 2; a1++){
            bfpack pk;
            pk.u[0] = cvtpk(ex2(svv[2*a1][0] - rm),   ex2(svv[2*a1][1] - rm));
            pk.u[1] = cvtpk(ex2(svv[2*a1][2] - rm),   ex2(svv[2*a1][3] - rm));
            pk.u[2] = cvtpk(ex2(svv[2*a1+1][0] - rm), ex2(svv[2*a1+1][1] - rm));
            pk.u[3] = cvtpk(ex2(svv[2*a1+1][2] - rm), ex2(svv[2*a1+1][3] - rm));
            bf8 ap = pk.v;
            racc = MFMA(ap, ones, racc);
            #pragma unroll
            for (int nb2 = 0; nb2 < 4; nb2++){
                bf8 bv = *(const bf8*)swzc(vtc, nb2*16 + lc, a1*4 + quad);
                oacc[nb2] = MFMA(ap, bv, oacc[nb2]);
            }
        }
        __syncthreads();   // one barrier/tile: drains shadow staging + ds_reads
        #pragma unroll
        for (int a1 = 0; a1 < 2; a1++)
            #pragma unroll
            for (int b1 = 0; b1 < 2; b1++)
                mv[a1][b1] = mvn[a1][b1];
        cur ^= 1;
    }
    // stats out: rm rows = lc (quad==0 lanes); l rows = quad*4+r (lc==0 lanes)
    size_t sbase = (size_t)half*65536 + ((size_t)(b*Hc+h))*Sc + qs0 + wv_*16;
    if (quad == 0) pm[sbase + lc] = rm;
    if (lc == 0){
        #pragma unroll
        for (int r = 0; r < 4; r++) pl[sbase + quad*4 + r] = racc[r];
    }
    // ctx normalized by this half's own l (racc rows match oacc rows)
    #pragma unroll
    for (int r = 0; r < 4; r++){
        float ir = 1.f/racc[r];
        int tok = qs0 + wv_*16 + quad*4 + r;
        #pragma unroll
        for (int nb = 0; nb < 4; nb++){
            int hd = nb*16 + lc;
            ctxh[((size_t)(b*Sc + tok))*Ec + h*HDc + hd] = f2b(oacc[nb][r]*ir);
        }
    }
}

// ---------------------------------------------------------------------------
// 9b. merge the two half stats -> combine weights + attnw constant.
// ---------------------------------------------------------------------------
__global__ __launch_bounds__(256) void k_merge(
    const float* __restrict__ pm, const float* __restrict__ pl,
    float* __restrict__ lstc, float* __restrict__ w0, float* __restrict__ w1)
{
    int r = blockIdx.x*256 + threadIdx.x;
    float m0 = pm[r],        m1 = pm[65536 + r];
    float l0 = pl[r],        l1 = pl[65536 + r];
    float M  = fmaxf(m0, m1);
    float e0 = ex2(m0 - M)*l0;
    float e1 = ex2(m1 - M)*l1;
    float L  = e0 + e1;
    float iL = 1.f/L;
    lstc[r] = M + log2f(L);
    w0[r] = e0*iL;
    w1[r] = e1*iL;
}

// ---------------------------------------------------------------------------
// 9c. weighted combine of the two ctx halves: c0 = w0*c0 + w1*c1
// ---------------------------------------------------------------------------
__global__ __launch_bounds__(256) void k_addc(u16* __restrict__ c0,
                                              const u16* __restrict__ c1,
                                              const float* __restrict__ w0,
                                              const float* __restrict__ w1)
{
    int i = (blockIdx.x*256 + threadIdx.x)*8;
    int hh = (i >> 6) & 15, s = (i >> 10) & 2047, bb = i >> 21;
    int wi = ((bb*Hc + hh) << 11) + s;
    float wa = w0[wi], wb = w1[wi];
    ushort4 a0 = *(ushort4*)&c0[i],   a1 = *(ushort4*)&c0[i+4];
    ushort4 b0 = *(const ushort4*)&c1[i], b1 = *(const ushort4*)&c1[i+4];
    ushort4 o0, o1;
    o0.x = f2b(b2f(a0.x)*wa + b2f(b0.x)*wb); o0.y = f2b(b2f(a0.y)*wa + b2f(b0.y)*wb);
    o0.z = f2b(b2f(a0.z)*wa + b2f(b0.z)*wb); o0.w = f2b(b2f(a0.w)*wa + b2f(b0.w)*wb);
    o1.x = f2b(b2f(a1.x)*wa + b2f(b1.x)*wb); o1.y = f2b(b2f(a1.y)*wa + b2f(b1.y)*wb);
    o1.z = f2b(b2f(a1.z)*wa + b2f(b1.z)*wb); o1.w = f2b(b2f(a1.w)*wa + b2f(b1.w)*wb);
    *(ushort4*)&c0[i]   = o0;
    *(ushort4*)&c0[i+4] = o1;
}

// ---------------------------------------------------------------------------
// 8. attn_weights: q-tile 64, k-tile 64, loop all 16 h, NO atomics.
//    grid (32, 32, 2) = (q, k, b). 2-phase double-buffered h-loop: stage
//    h+1 (gl16 K + scc + aq regs) before computing h; one barrier/iter.
// ---------------------------------------------------------------------------
__global__ __launch_bounds__(256) void k_attnw(
    const u16* __restrict__ qb, const u16* __restrict__ kb,
    const u16* __restrict__ maskb, const float* __restrict__ lstc,
    float* __restrict__ awout)
{
    int qs0 = blockIdx.x*64, ks0 = blockIdx.y*64, b = blockIdx.z;
    int t = threadIdx.x, lane = t & 63, wv_ = t >> 6;
    int quad = lane >> 4, lc = lane & 15;
    __shared__ u16 kt[2][64*64];
    __shared__ float scc[2][64];
    f32x4 T[4];
    #pragma unroll
    for (int j=0;j<4;j++) T[j] = (f32x4){0.f,0.f,0.f,0.f};

    int lsub = lane >> 3;
    int colsw = ((lane & 7) ^ lsub) << 3;
    int lrA = wv_*16 + lsub, lrB = wv_*16 + 8 + lsub;
    int kdo0 = (wv_*16 + 0)*64, kdo1 = (wv_*16 + 8)*64;
    size_t qoff = (size_t)(qs0 + wv_*16 + lc)*HDc;

    // prologue: stage h=0
    {
        const u16* kp = kb + ((size_t)(b*Hc+0))*Sc*HDc;
        gl16(kp + (size_t)(ks0 + lrA)*HDc + colsw, &kt[0][kdo0]);
        gl16(kp + (size_t)(ks0 + lrB)*HDc + colsw, &kt[0][kdo1]);
        if (t < 64) scc[0][t] = lstc[((size_t)(b*Hc+0))*Sc + qs0 + t];
    }
    bf8 aq[2];
    #pragma unroll
    for (int ks = 0; ks < 2; ks++)
        aq[ks] = *(const bf8*)(qb + ((size_t)(b*Hc+0))*Sc*HDc + qoff + ks*32 + quad*8);
    __syncthreads();

    int cur = 0;
    for (int h = 0; h < Hc; h++){
        // stage next h (clamped on last)
        int hn = (h + 1 < Hc) ? h + 1 : h;
        {
            const u16* kpn = kb + ((size_t)(b*Hc+hn))*Sc*HDc;
            gl16(kpn + (size_t)(ks0 + lrA)*HDc + colsw, &kt[cur^1][kdo0]);
            gl16(kpn + (size_t)(ks0 + lrB)*HDc + colsw, &kt[cur^1][kdo1]);
            if (t < 64) scc[cur^1][t] = lstc[((size_t)(b*Hc+hn))*Sc + qs0 + t];
        }
        bf8 aqn[2];
        #pragma unroll
        for (int ks = 0; ks < 2; ks++)
            aqn[ks] = *(const bf8*)(qb + ((size_t)(b*Hc+hn))*Sc*HDc + qoff + ks*32 + quad*8);

        const u16* ktc = kt[cur];
        f32x4 acc[4];
        #pragma unroll
        for (int j=0;j<4;j++) acc[j] = (f32x4){0.f,0.f,0.f,0.f};
        #pragma unroll
        for (int ks = 0; ks < 2; ks++){
            #pragma unroll
            for (int nb = 0; nb < 4; nb++){
                bf8 bbv = *(const bf8*)swzc(ktc, nb*16 + lc, ks*4 + quad);
                acc[nb] = MFMA(aq[ks], bbv, acc[nb]);
            }
        }
        #pragma unroll
        for (int r = 0; r < 4; r++){
            int row = wv_*16 + quad*4 + r;
            float cv = scc[cur][row];
            #pragma unroll
            for (int nb = 0; nb < 4; nb++)
                T[nb][r] += ex2(acc[nb][r] - cv);
        }
        __syncthreads();
        aq[0] = aqn[0]; aq[1] = aqn[1];
        cur ^= 1;
    }
    #pragma unroll
    for (int r = 0; r < 4; r++){
        int gq = qs0 + wv_*16 + quad*4 + r;
        #pragma unroll
        for (int nb = 0; nb < 4; nb++){
            int gk = ks0 + nb*16 + lc;
            float mk = b2f(maskb[(size_t)gq*Sc + gk]);   // mask*log2e
            awout[(size_t)b*Sc*Sc + (size_t)gq*Sc + gk]
                = T[nb][r]*ex2(mk)*(1.f/16.f);
        }
    }
}

// ---------------------------------------------------------------------------
// 10. output projection, MFMA. grid (8, NTILES). XOR-swizzled tiles staged
//     via global_load_lds (same mapping as k_qkv).
// ---------------------------------------------------------------------------
__global__ __launch_bounds__(256) void k_oproj(
    const u16* __restrict__ ctxb, const u16* __restrict__ woT,
    const int* __restrict__ perm, const int* __restrict__ tmeta,
    const u16* __restrict__ zbuf, float* __restrict__ opre)
{
    int meta = tmeta[blockIdx.y];
    if (meta < 0) return;
    int b = meta >> 1, m = meta & 1;
    const u16* W = woT + (size_t)m*Ec*Dc;
    int c0 = blockIdx.x*128;
    int t = threadIdx.x, lane = t & 63, wv_ = t >> 6;
    int quad = lane >> 4, lc = lane & 15;
    __shared__ u16 at[128*64];
    __shared__ u16 bt[128*64];
    __shared__ int sperm[128];
    if (t < 128) sperm[t] = perm[blockIdx.y*128 + t];
    f32x4 acc[2][8];
    #pragma unroll
    for (int i=0;i<2;i++)
        #pragma unroll
        for (int j=0;j<8;j++) acc[i][j] = (f32x4){0.f,0.f,0.f,0.f};
    __syncthreads();

    int colsw = ((lane & 7) ^ (lane >> 3)) << 3;
    const u16* ab[4]; const u16* bb[4];
    #pragma unroll
    for (int i = 0; i < 4; i++){
        int row = wv_*32 + i*8 + (lane >> 3);
        int s_ = sperm[row];
        ab[i] = (s_ >= 0) ? (ctxb + ((size_t)(b*Sc + s_))*Ec + colsw) : zbuf;
        bb[i] = W + (size_t)(c0 + row)*Ec + colsw;
    }

    for (int d0 = 0; d0 < Ec; d0 += 64){
        #pragma unroll
        for (int i = 0; i < 4; i++){
            gl16(ab[i] + d0, &at[(wv_*4 + i)*512]);
            gl16(bb[i] + d0, &bt[(wv_*4 + i)*512]);
        }
        __syncthreads();
        #pragma unroll
        for (int ks = 0; ks < 2; ks++){
            bf8 a0 = *(const bf8*)swzc(at, wv_*32 + lc,      ks*4 + quad);
            bf8 a1 = *(const bf8*)swzc(at, wv_*32 + 16 + lc, ks*4 + quad);
            #pragma unroll
            for (int nb = 0; nb < 8; nb++){
                bf8 bb2 = *(const bf8*)swzc(bt, nb*16 + lc, ks*4 + quad);
                acc[0][nb] = MFMA(a0, bb2, acc[0][nb]);
                acc[1][nb] = MFMA(a1, bb2, acc[1][nb]);
            }
        }
        __syncthreads();
    }
    #pragma unroll
    for (int mb = 0; mb < 2; mb++){
        #pragma unroll
        for (int r = 0; r < 4; r++){
            int row = wv_*32 + mb*16 + quad*4 + r;
            int s_ = sperm[row];
            if (s_ < 0) continue;
            #pragma unroll
            for (int nb = 0; nb < 8; nb++){
                int col = c0 + nb*16 + lc;
                opre[((size_t)(b*Sc + s_))*Dc + col] = acc[mb][nb][r];
            }
        }
    }
}

// ---------------------------------------------------------------------------
// 11. final RMSNorm over D -> out
// ---------------------------------------------------------------------------
__global__ __launch_bounds__(256) void k_onorm(
    const float* __restrict__ opre, const float* __restrict__ anw,
    const int* __restrict__ mod, float* __restrict__ out)
{
    int row = blockIdx.x;
    int m = mod[row];
    int t = threadIdx.x;
    float val[4];
    float ss = 0.f;
    #pragma unroll
    for (int j=0;j<4;j++){
        val[j] = opre[(size_t)row*Dc + t + 256*j];
        ss += val[j]*val[j];
    }
    #pragma unroll
    for (int o=32;o>0;o>>=1) ss += __shfl_xor(ss, o, 64);
    __shared__ float red[4];
    int wid = t>>6, lane = t&63;
    if (lane==0) red[wid]=ss;
    __syncthreads();
    float tot = red[0]+red[1]+red[2]+red[3];
    float rms = rsqrtf(tot*(1.f/1024.f) + EPSc);
    #pragma unroll
    for (int j=0;j<4;j++)
        out[(size_t)row*Dc + t + 256*j] = val[j]*rms*anw[m*Dc + t + 256*j];
}

// ---------------------------------------------------------------------------
extern "C" void kernel_launch(void* const* d_in, const int* in_sizes, int n_in,
                              void* d_out, int out_size, void* d_ws, size_t ws_size,
                              hipStream_t stream)
{
    const float* x    = (const float*)d_in[0];
    const float* mask = (const float*)d_in[1];
    const int*   mod  = (const int*)  d_in[2];
    const float* Wq   = (const float*)d_in[3];
    const float* Wk   = (const float*)d_in[4];
    const float* Wv   = (const float*)d_in[5];
    const float* Wo   = (const float*)d_in[6];
    const float* qnw  = (const float*)d_in[7];
    const float* knw  = (const float*)d_in[8];
    const float* anw  = (const float*)d_in[9];

    float* out   = (float*)d_out;                 // [B,S,D]
    float* awout = out + (size_t)Bc*Sc*Dc;        // [B,S,S]

    float* ws = (float*)d_ws;
    u16* qb    = (u16*)(ws + 0);
    u16* kb    = (u16*)(ws + 2097152);
    u16* vb    = (u16*)(ws + 4194304);   // dead after k_vt -> ctx partial 1
    u16* xb    = (u16*)(ws + 6291456);   // dead after k_qkv -> ctx partial 0
    u16* ctx0  = xb;
    u16* ctx1  = vb;
    u16* vtb   = (u16*)(ws + 8388608);
    u16* wqT   = (u16*)(ws + 10485760);
    u16* wkT   = (u16*)(ws + 11534336);
    u16* wvT   = (u16*)(ws + 12582912);
    u16* woT   = (u16*)(ws + 13631488);
    float* lstc= ws + 14680064;          // M + log2(L), 65536
    float* pm  = ws + 14811136;          // per-half m, 2*65536
    float* pl  = pm + 131072;            // per-half l, 2*65536
    float* w0  = ws + 15073280;          // combine weights, 65536 each
    float* w1  = w0 + 65536;
    u16* maskb = (u16*)(ws + 15335424);  // mask*log2e, bf16
    int* perm  = (int*)(ws + 17432576);
    int* tmeta = perm + NTILES*TILE_R;
    u16* zbuf  = (u16*)(tmeta + NTILES + 28);   // 4KB zero scratch (aligned)
    float* opre = ws;                    // aliases qb+kb (dead by then)

    k_perm  <<<dim3(1),            256, 0, stream>>>(mod, perm, tmeta, zbuf);
    k_prep  <<<dim3(8192),         256, 0, stream>>>(x, mask, xb, maskb);
    k_tcvt  <<<dim3(32,32,8),      256, 0, stream>>>(Wq, Wk, Wv, Wo, wqT, wkT, wvT, woT);
    k_qkv   <<<dim3(8,NTILES,3),   256, 0, stream>>>(xb, wqT, wkT, wvT, perm, tmeta,
                                                     qnw, knw, zbuf, qb, kb, vb);
    k_vt    <<<dim3(32,32),        256, 0, stream>>>(vb, vtb);
    k_flash <<<dim3(32,16,4),      256, 0, stream>>>(qb, kb, vtb, maskb, pm, pl, ctx0, ctx1);
    k_merge <<<dim3(256),          256, 0, stream>>>(pm, pl, lstc, w0, w1);
    k_attnw <<<dim3(32,32,2),      256, 0, stream>>>(qb, kb, maskb, lstc, awout);
    k_addc  <<<dim3(2048),         256, 0, stream>>>(ctx0, ctx1, w0, w1);
    k_oproj <<<dim3(8,NTILES),     256, 0, stream>>>(ctx0, woT, perm, tmeta, zbuf, opre);
    k_onorm <<<dim3(4096),         256, 0, stream>>>(opre, anw, mod, out);
}

// Round 10
// 345.711 us; speedup vs baseline: 1.1203x; 1.1203x over previous
//
#include <hip/hip_runtime.h>
#include <cstdint>

#define Bc  2
#define Sc  2048
#define Dc  1024
#define Ec  1024
#define Hc  16
#define HDc 64
#define TTc (Bc*Sc)
#define TILE_R 128
#define NTILES 36
#define EPSc 1e-5f
#define LOG2E 1.44269504f
#define C2    (0.125f*LOG2E)

typedef unsigned short u16;
using bf8   = __attribute__((ext_vector_type(8))) short;
using f32x4 = __attribute__((ext_vector_type(4))) float;
#define MFMA(a,b,c) __builtin_amdgcn_mfma_f32_16x16x32_bf16(a,b,c,0,0,0)

static __device__ __forceinline__ u16 f2b(float f){
    return (u16)((__float_as_uint(f) + 0x8000u) >> 16);
}
static __device__ __forceinline__ float b2f(u16 s){
    return __uint_as_float(((unsigned)s) << 16);
}
// raw v_exp_f32 (2^x): inputs here are <= ~8; underflow flushes to 0 which is
// exactly the wanted semantics. Avoids OCML's multi-instruction wrapper.
static __device__ __forceinline__ float ex2(float x){
    return __builtin_amdgcn_exp2f(x);
}
// pack two f32 -> one dword of 2 bf16 (low = a, high = b), single VALU op
static __device__ __forceinline__ unsigned cvtpk(float a, float b){
    unsigned r;
    asm("v_cvt_pk_bf16_f32 %0, %1, %2" : "=v"(r) : "v"(a), "v"(b));
    return r;
}
union bfpack { unsigned u[4]; bf8 v; };
// 3-input max; clang fuses to v_max3_f32
static __device__ __forceinline__ float max3f(float a, float b, float c){
    return fmaxf(fmaxf(a, b), c);
}
// XOR-swizzled LDS addressing: tiles are [R][64] u16, 8-u16 (16B) groups,
// group index col8 swizzled by row&7 -> fragment ds_read_b128 is
// bank-conflict-free.
static __device__ __forceinline__ u16* swz(u16* base, int row, int col8){
    return base + row*64 + ((col8 ^ (row & 7)) << 3);
}
static __device__ __forceinline__ const u16* swzc(const u16* base, int row, int col8){
    return base + row*64 + ((col8 ^ (row & 7)) << 3);
}
// async global->LDS, 16B per lane. LDS dest = wave-uniform base + lane*16
// (linear); the swizzle is applied by inverse-permuting the per-lane global
// source address (rule: linear dest + inv-swz source + swz read).
typedef const __attribute__((address_space(1))) void* gp1;
typedef __attribute__((address_space(3))) void* lp3;
static __device__ __forceinline__ void gl16(const void* g, void* l){
    __builtin_amdgcn_global_load_lds((gp1)g, (lp3)l, 16, 0, 0);
}
// inverse of the k_flash pi row permutation (pi: pr4=g2, pr3=g4, pr2=g3)
static __device__ __forceinline__ int pinv(int lr){
    return (lr & 0x23) | ((lr & 0x10) >> 2) | ((lr & 0x0C) << 1);
}

// ---------------------------------------------------------------------------
// 1. modality-sorted token permutation, 128-padded segments per (b,m).
//    Also zeroes the 4KB zbuf used by gload_lds staging for padding rows.
// ---------------------------------------------------------------------------
__global__ void k_perm(const int* __restrict__ mod, int* __restrict__ perm,
                       int* __restrict__ tmeta, u16* __restrict__ zbuf)
{
    __shared__ int cnt[4], segstart[4];
    int t = threadIdx.x;
    for (int i = t; i < 2048; i += 256) zbuf[i] = 0;
    if (t < 4) cnt[t] = 0;
    __syncthreads();
    for (int i = t; i < TTc; i += 256){
        int b = i >> 11; int m = mod[i];
        atomicAdd(&cnt[b*2+m], 1);
    }
    __syncthreads();
    if (t == 0){
        int off = 0;
        for (int i = 0; i < 4; i++){
            segstart[i] = off;
            int pad = ((cnt[i] + TILE_R - 1)/TILE_R)*TILE_R;
            for (int tt = off/TILE_R; tt < (off+pad)/TILE_R; tt++) tmeta[tt] = i;
            off += pad;
        }
        for (int tt = off/TILE_R; tt < NTILES; tt++) tmeta[tt] = -1;
    }
    __syncthreads();
    if (t < 4) cnt[t] = 0;
    for (int i = t; i < NTILES*TILE_R; i += 256) perm[i] = -1;
    __syncthreads();
    for (int i = t; i < TTc; i += 256){
        int b = i >> 11, s = i & 2047; int m = mod[i];
        int r = atomicAdd(&cnt[b*2+m], 1);
        perm[segstart[b*2+m] + r] = s;
    }
}

// ---------------------------------------------------------------------------
// 2. fused fp32->bf16 conversion: x (plain) + mask (scaled by LOG2E).
//    grid 8192: blocks [0,4096) -> x, [4096,8192) -> mask.
// ---------------------------------------------------------------------------
__global__ __launch_bounds__(256) void k_prep(
    const float* __restrict__ x, const float* __restrict__ mask,
    u16* __restrict__ xb, u16* __restrict__ maskb)
{
    int bid = blockIdx.x;
    if (bid < 4096){
        int i = (bid*256 + threadIdx.x)*4;
        float4 v = *(const float4*)&x[i];
        ushort4 o;
        o.x = f2b(v.x); o.y = f2b(v.y); o.z = f2b(v.z); o.w = f2b(v.w);
        *(ushort4*)&xb[i] = o;
    } else {
        int i = ((bid-4096)*256 + threadIdx.x)*4;
        float4 v = *(const float4*)&mask[i];
        ushort4 o;
        o.x = f2b(v.x*LOG2E); o.y = f2b(v.y*LOG2E);
        o.z = f2b(v.z*LOG2E); o.w = f2b(v.w*LOG2E);
        *(ushort4*)&maskb[i] = o;
    }
}

// ---------------------------------------------------------------------------
// 3. transpose+convert all four weights in one launch; grid (32,32,8)
// ---------------------------------------------------------------------------
__global__ __launch_bounds__(256) void k_tcvt(
    const float* __restrict__ s0, const float* __restrict__ s1,
    const float* __restrict__ s2, const float* __restrict__ s3,
    u16* __restrict__ d0, u16* __restrict__ d1,
    u16* __restrict__ d2, u16* __restrict__ d3)
{
    int wsel = blockIdx.z >> 1, m = blockIdx.z & 1;
    const float* src = (wsel==0?s0:wsel==1?s1:wsel==2?s2:s3) + (size_t)m*1048576;
    u16*       dst = (wsel==0?d0:wsel==1?d1:wsel==2?d2:d3) + (size_t)m*1048576;
    __shared__ float sh[32][33];
    int t = threadIdx.x;
    int i0 = blockIdx.x*32, j0 = blockIdx.y*32;
    {
        int i = t >> 3, j4 = (t & 7)*4;
        *(float4*)&sh[i][j4] = *(const float4*)&src[(size_t)(i0+i)*1024 + j0 + j4];
    }
    __syncthreads();
    {
        int j = t >> 3, i4 = (t & 7)*4;
        ushort4 o;
        o.x = f2b(sh[i4+0][j]); o.y = f2b(sh[i4+1][j]);
        o.z = f2b(sh[i4+2][j]); o.w = f2b(sh[i4+3][j]);
        *(ushort4*)&dst[(size_t)(j0+j)*1024 + i0 + i4] = o;
    }
}

// ---------------------------------------------------------------------------
// 4. QKV projection, MFMA, fused per-head RMSNorm for Q and K.
//    grid (8, NTILES, 3). LDS tiles XOR-swizzled [128][64], staged via
//    global_load_lds (linear dest, inverse-swizzled per-lane source).
//    Q folded with C2 = 0.125*log2e.
// ---------------------------------------------------------------------------
__global__ __launch_bounds__(256) void k_qkv(
    const u16* __restrict__ xb, const u16* __restrict__ wqT,
    const u16* __restrict__ wkT, const u16* __restrict__ wvT,
    const int* __restrict__ perm, const int* __restrict__ tmeta,
    const float* __restrict__ qnw, const float* __restrict__ knw,
    const u16* __restrict__ zbuf,
    u16* __restrict__ qb, u16* __restrict__ kb, u16* __restrict__ vb)
{
    int meta = tmeta[blockIdx.y];
    if (meta < 0) return;
    int b = meta >> 1, m = meta & 1;
    const u16* W = (blockIdx.z==0 ? wqT : (blockIdx.z==1 ? wkT : wvT)) + (size_t)m*Ec*Dc;
    u16* outp    = (blockIdx.z==0 ? qb  : (blockIdx.z==1 ? kb  : vb));
    int c0 = blockIdx.x*128;
    int t = threadIdx.x, lane = t & 63, wv_ = t >> 6;
    int quad = lane >> 4, lc = lane & 15;

    __shared__ u16 at[128*64];
    __shared__ u16 bt[128*64];
    __shared__ int sperm[128];
    if (t < 128) sperm[t] = perm[blockIdx.y*128 + t];
    f32x4 acc[2][8];
    #pragma unroll
    for (int i=0;i<2;i++)
        #pragma unroll
        for (int j=0;j<8;j++) acc[i][j] = (f32x4){0.f,0.f,0.f,0.f};
    __syncthreads();

    // staging sources: wave w instr i lane l covers LDS row w*32+i*8+(l>>3),
    // stored group l&7 -> true col8 = (l&7)^(l>>3) (row&7 == l>>3).
    int colsw = ((lane & 7) ^ (lane >> 3)) << 3;
    const u16* ab[4]; const u16* bb[4];
    #pragma unroll
    for (int i = 0; i < 4; i++){
        int row = wv_*32 + i*8 + (lane >> 3);
        int s_ = sperm[row];
        ab[i] = (s_ >= 0) ? (xb + ((size_t)(b*Sc + s_))*Dc + colsw) : zbuf;
        bb[i] = W + (size_t)(c0 + row)*Dc + colsw;
    }

    for (int d0 = 0; d0 < Dc; d0 += 64){
        #pragma unroll
        for (int i = 0; i < 4; i++){
            gl16(ab[i] + d0, &at[(wv_*4 + i)*512]);
            gl16(bb[i] + d0, &bt[(wv_*4 + i)*512]);
        }
        __syncthreads();
        #pragma unroll
        for (int ks = 0; ks < 2; ks++){
            bf8 a0 = *(const bf8*)swzc(at, wv_*32 + lc,      ks*4 + quad);
            bf8 a1 = *(const bf8*)swzc(at, wv_*32 + 16 + lc, ks*4 + quad);
            #pragma unroll
            for (int nb = 0; nb < 8; nb++){
                bf8 bb2 = *(const bf8*)swzc(bt, nb*16 + lc, ks*4 + quad);
                acc[0][nb] = MFMA(a0, bb2, acc[0][nb]);
                acc[1][nb] = MFMA(a1, bb2, acc[1][nb]);
            }
        }
        __syncthreads();
    }

    if (blockIdx.z < 2){
        const float* nw = (blockIdx.z==0 ? qnw : knw) + m*HDc;
        float cs = (blockIdx.z==0) ? C2 : 1.f;   // fold score scale into Q
        float w0 = nw[lc]*cs, w1 = nw[16+lc]*cs, w2 = nw[32+lc]*cs, w3 = nw[48+lc]*cs;
        #pragma unroll
        for (int mb = 0; mb < 2; mb++){
            #pragma unroll
            for (int r = 0; r < 4; r++){
                #pragma unroll
                for (int g = 0; g < 2; g++){
                    float ss = 0.f;
                    #pragma unroll
                    for (int j = 0; j < 4; j++){
                        float v2 = acc[mb][g*4+j][r];
                        ss += v2*v2;
                    }
                    ss += __shfl_xor(ss, 1, 64);
                    ss += __shfl_xor(ss, 2, 64);
                    ss += __shfl_xor(ss, 4, 64);
                    ss += __shfl_xor(ss, 8, 64);
                    float rs = rsqrtf(ss*(1.f/64.f) + EPSc);
                    acc[mb][g*4+0][r] *= rs*w0;
                    acc[mb][g*4+1][r] *= rs*w1;
                    acc[mb][g*4+2][r] *= rs*w2;
                    acc[mb][g*4+3][r] *= rs*w3;
                }
            }
        }
    }

    int h0 = c0 >> 6;
    #pragma unroll
    for (int mb = 0; mb < 2; mb++){
        #pragma unroll
        for (int r = 0; r < 4; r++){
            int row = wv_*32 + mb*16 + quad*4 + r;
            int s_ = sperm[row];
            if (s_ < 0) continue;
            #pragma unroll
            for (int nb = 0; nb < 8; nb++){
                int col = nb*16 + lc;
                int h = h0 + (col >> 6), hd = col & 63;
                outp[(((size_t)(b*Hc + h))*Sc + s_)*HDc + hd] = f2b(acc[mb][nb][r]);
            }
        }
    }
}

// ---------------------------------------------------------------------------
// 6. V transpose via LDS tiles: vb [BH][S][HD] -> vtb [BH][HD][S]
// ---------------------------------------------------------------------------
__global__ __launch_bounds__(256) void k_vt(const u16* __restrict__ vb,
                                            u16* __restrict__ vtb)
{
    __shared__ u16 sh[64][72];
    int t = threadIdx.x;
    int s0 = blockIdx.x*64, bh = blockIdx.y;
    {
        int rr = t >> 2, cc = (t & 3)*16;
        const u16* src = vb + ((size_t)bh*Sc + s0 + rr)*HDc + cc;
        *(uint4*)&sh[rr][cc]   = *(const uint4*)(src);
        *(uint4*)&sh[rr][cc+8] = *(const uint4*)(src+8);
    }
    __syncthreads();
    {
        int hd = t >> 2, sc = (t & 3)*16;
        u16 tmp[16];
        #pragma unroll
        for (int j = 0; j < 16; j++) tmp[j] = sh[sc+j][hd];
        u16* dst = vtb + ((size_t)bh*HDc + hd)*Sc + s0 + sc;
        *(uint4*)(dst)   = *(const uint4*)&tmp[0];
        *(uint4*)(dst+8) = *(const uint4*)&tmp[8];
    }
}

// ---------------------------------------------------------------------------
// 9. flash PV with ONLINE softmax + defer-max (THR=8), split-K x2:
//    grid (32, 16, 4): z = b*2 + half.
//    2-PHASE DOUBLE-BUFFERED PIPELINE (T3 minimum recipe): stage tile t+1
//    (gl16 K/V + mask regs) at loop top, compute tile t, ONE barrier/tile.
//    Swapped QK^T + pi-permuted K keeps P in registers in exact PV A-frag
//    layout. Row-sum l via MFMA ones-operand (racc rows == oacc rows).
//    max3 tree, cvt_pk pack, native v_exp_f32, defer-max.
// ---------------------------------------------------------------------------
__global__ __launch_bounds__(256) void k_flash(
    const u16* __restrict__ qb, const u16* __restrict__ kb,
    const u16* __restrict__ vtb, const u16* __restrict__ maskb,
    float* __restrict__ pm, float* __restrict__ pl,
    u16* __restrict__ c0, u16* __restrict__ c1)
{
    int qs0 = blockIdx.x*64, h = blockIdx.y;
    int b = blockIdx.z >> 1, half = blockIdx.z & 1;
    u16* ctxh = half ? c1 : c0;
    int t = threadIdx.x, lane = t & 63, wv_ = t >> 6;
    int quad = lane >> 4, lc = lane & 15;
    __shared__ u16 kt[2][64*64];
    __shared__ u16 vt[2][64*64];
    const u16* qp  = qb  + ((size_t)(b*Hc+h))*Sc*HDc;
    const u16* kp  = kb  + ((size_t)(b*Hc+h))*Sc*HDc;
    const u16* vtp = vtb + ((size_t)(b*Hc+h))*HDc*Sc;
    const u16* mq  = maskb + (size_t)(qs0 + wv_*16 + lc)*Sc;  // this lane's q-row
    bf8 aq[2];
    #pragma unroll
    for (int ks = 0; ks < 2; ks++)
        aq[ks] = *(const bf8*)(qp + (size_t)(qs0 + wv_*16 + lc)*HDc + ks*32 + quad*8);
    // all-ones B fragment for MFMA row sums
    bfpack onep; onep.u[0] = onep.u[1] = onep.u[2] = onep.u[3] = 0x3F803F80u;
    bf8 ones = onep.v;
    // online stats: rm per-lane for q-row lc; l via racc (rows quad*4+r)
    float rm = -1.0e30f;
    f32x4 racc = (f32x4){0.f,0.f,0.f,0.f};
    f32x4 oacc[4];
    #pragma unroll
    for (int j=0;j<4;j++) oacc[j] = (f32x4){0.f,0.f,0.f,0.f};

    // gl16 staging geometry (per wave: rows w*16..w*16+15 of each tile)
    int lsub = lane >> 3;
    int colsw = ((lane & 7) ^ lsub) << 3;
    int lrA = wv_*16 + lsub, lrB = wv_*16 + 8 + lsub;
    const u16* kg0 = kp + (size_t)pinv(lrA)*HDc + colsw;
    const u16* kg1 = kp + (size_t)pinv(lrB)*HDc + colsw;
    const u16* vg0 = vtp + (size_t)lrA*Sc + colsw;
    const u16* vg1 = vtp + (size_t)lrB*Sc + colsw;
    int kdo0 = (wv_*16 + 0)*64, kdo1 = (wv_*16 + 8)*64;

    int kc0 = half*1024, kcend = kc0 + 1024;
    // prologue: stage tile 0 into buffer 0, prefetch its mask
    gl16(kg0 + (size_t)kc0*HDc, &kt[0][kdo0]);
    gl16(kg1 + (size_t)kc0*HDc, &kt[0][kdo1]);
    gl16(vg0 + kc0, &vt[0][kdo0]);
    gl16(vg1 + kc0, &vt[0][kdo1]);
    ushort4 mv[2][2];
    #pragma unroll
    for (int a1 = 0; a1 < 2; a1++)
        #pragma unroll
        for (int b1 = 0; b1 < 2; b1++)
            mv[a1][b1] = *(const ushort4*)(mq + kc0 + a1*32 + quad*8 + b1*4);
    __syncthreads();   // drains prologue staging -> buffer 0 ready

    int cur = 0;
    for (int kc = kc0; kc < kcend; kc += 64){
        // stage NEXT tile into the shadow buffer (clamped on last iter;
        // redundant loads land in the unused buffer, drained by last barrier)
        int nxt = (kc + 64 < kcend) ? kc + 64 : kc;
        gl16(kg0 + (size_t)nxt*HDc, &kt[cur^1][kdo0]);
        gl16(kg1 + (size_t)nxt*HDc, &kt[cur^1][kdo1]);
        gl16(vg0 + nxt, &vt[cur^1][kdo0]);
        gl16(vg1 + nxt, &vt[cur^1][kdo1]);
        ushort4 mvn[2][2];
        #pragma unroll
        for (int a1 = 0; a1 < 2; a1++)
            #pragma unroll
            for (int b1 = 0; b1 < 2; b1++)
                mvn[a1][b1] = *(const ushort4*)(mq + nxt + a1*32 + quad*8 + b1*4);

        const u16* ktc = kt[cur];
        const u16* vtc = vt[cur];
        // S^T = K * Q^T (Q pre-scaled by C2)
        f32x4 acc[4];
        #pragma unroll
        for (int j=0;j<4;j++) acc[j] = (f32x4){0.f,0.f,0.f,0.f};
        #pragma unroll
        for (int ks = 0; ks < 2; ks++){
            #pragma unroll
            for (int nb = 0; nb < 4; nb++){
                bf8 ak = *(const bf8*)swzc(ktc, nb*16 + lc, ks*4 + quad);
                acc[nb] = MFMA(ak, aq[ks], acc[nb]);
            }
        }
        // scores + mask; per-lane max via max3 tree
        float svv[4][4];
        #pragma unroll
        for (int a1 = 0; a1 < 2; a1++){
            #pragma unroll
            for (int b1 = 0; b1 < 2; b1++){
                int nb = 2*a1 + b1;
                #pragma unroll
                for (int r = 0; r < 4; r++){
                    u16 mraw = (r==0?mv[a1][b1].x:r==1?mv[a1][b1].y:
                                r==2?mv[a1][b1].z:mv[a1][b1].w);
                    svv[nb][r] = acc[nb][r] + b2f(mraw);
                }
            }
        }
        float m0_ = max3f(svv[0][0], svv[0][1], svv[0][2]);
        float m1_ = max3f(svv[0][3], svv[1][0], svv[1][1]);
        float m2_ = max3f(svv[1][2], svv[1][3], svv[2][0]);
        float m3_ = max3f(svv[2][1], svv[2][2], svv[2][3]);
        float m4_ = max3f(svv[3][0], svv[3][1], svv[3][2]);
        float mxl = fmaxf(max3f(m0_, m1_, m2_), max3f(m3_, m4_, svv[3][3]));
        // defer-max: only reduce/rescale when some lane grew past rm + 8
        if (__any(mxl > rm + 8.f)){
            float mx = fmaxf(mxl, __shfl_xor(mxl, 16, 64));
            mx = fmaxf(mx, __shfl_xor(mx, 32, 64));
            float nm = fmaxf(rm, mx);
            float fac = ex2(rm - nm);
            rm = nm;
            float f0 = __shfl(fac, quad*4+0, 64);
            float f1 = __shfl(fac, quad*4+1, 64);
            float f2 = __shfl(fac, quad*4+2, 64);
            float f3 = __shfl(fac, quad*4+3, 64);
            racc[0] *= f0; racc[1] *= f1; racc[2] *= f2; racc[3] *= f3;
            #pragma unroll
            for (int nb = 0; nb < 4; nb++){
                oacc[nb][0] *= f0; oacc[nb][1] *= f1;
                oacc[nb][2] *= f2; oacc[nb][3] *= f3;
            }
        }
        // P (bounded by 2^8) packed via cvt_pk straight into PV A-fragments;
        // row sums accumulated on the matrix pipe via the ones fragment.
        #pragma unroll
        for (int a1 = 0; a1 < 2; a1++){
            bfpack pk;
            pk.u[0] = cvtpk(ex2(svv[2*a1][0] - rm),   ex2(svv[2*a1][1] - rm));
            pk.u[1] = cvtpk(ex2(svv[2*a1][2] - rm),   ex2(svv[2*a1][3] - rm));
            pk.u[2] = cvtpk(ex2(svv[2*a1+1][0] - rm), ex2(svv[2*a1+1][1] - rm));
            pk.u[3] = cvtpk(ex2(svv[2*a1+1][2] - rm), ex2(svv[2*a1+1][3] - rm));
            bf8 ap = pk.v;
            racc = MFMA(ap, ones, racc);
            #pragma unroll
            for (int nb2 = 0; nb2 < 4; nb2++){
                bf8 bv = *(const bf8*)swzc(vtc, nb2*16 + lc, a1*4 + quad);
                oacc[nb2] = MFMA(ap, bv, oacc[nb2]);
            }
        }
        __syncthreads();   // one barrier/tile: drains shadow staging + ds_reads
        #pragma unroll
        for (int a1 = 0; a1 < 2; a1++)
            #pragma unroll
            for (int b1 = 0; b1 < 2; b1++)
                mv[a1][b1] = mvn[a1][b1];
        cur ^= 1;
    }
    // stats out: rm rows = lc (quad==0 lanes); l rows = quad*4+r (lc==0 lanes)
    size_t sbase = (size_t)half*65536 + ((size_t)(b*Hc+h))*Sc + qs0 + wv_*16;
    if (quad == 0) pm[sbase + lc] = rm;
    if (lc == 0){
        #pragma unroll
        for (int r = 0; r < 4; r++) pl[sbase + quad*4 + r] = racc[r];
    }
    // ctx normalized by this half's own l (racc rows match oacc rows)
    #pragma unroll
    for (int r = 0; r < 4; r++){
        float ir = 1.f/racc[r];
        int tok = qs0 + wv_*16 + quad*4 + r;
        #pragma unroll
        for (int nb = 0; nb < 4; nb++){
            int hd = nb*16 + lc;
            ctxh[((size_t)(b*Sc + tok))*Ec + h*HDc + hd] = f2b(oacc[nb][r]*ir);
        }
    }
}

// ---------------------------------------------------------------------------
// 9b. merge the two half stats -> combine weights + attnw constant.
// ---------------------------------------------------------------------------
__global__ __launch_bounds__(256) void k_merge(
    const float* __restrict__ pm, const float* __restrict__ pl,
    float* __restrict__ lstc, float* __restrict__ w0, float* __restrict__ w1)
{
    int r = blockIdx.x*256 + threadIdx.x;
    float m0 = pm[r],        m1 = pm[65536 + r];
    float l0 = pl[r],        l1 = pl[65536 + r];
    float M  = fmaxf(m0, m1);
    float e0 = ex2(m0 - M)*l0;
    float e1 = ex2(m1 - M)*l1;
    float L  = e0 + e1;
    float iL = 1.f/L;
    lstc[r] = M + log2f(L);
    w0[r] = e0*iL;
    w1[r] = e1*iL;
}

// ---------------------------------------------------------------------------
// 9c. weighted combine of the two ctx halves: c0 = w0*c0 + w1*c1
// ---------------------------------------------------------------------------
__global__ __launch_bounds__(256) void k_addc(u16* __restrict__ c0,
                                              const u16* __restrict__ c1,
                                              const float* __restrict__ w0,
                                              const float* __restrict__ w1)
{
    int i = (blockIdx.x*256 + threadIdx.x)*8;
    int hh = (i >> 6) & 15, s = (i >> 10) & 2047, bb = i >> 21;
    int wi = ((bb*Hc + hh) << 11) + s;
    float wa = w0[wi], wb = w1[wi];
    ushort4 a0 = *(ushort4*)&c0[i],   a1 = *(ushort4*)&c0[i+4];
    ushort4 b0 = *(const ushort4*)&c1[i], b1 = *(const ushort4*)&c1[i+4];
    ushort4 o0, o1;
    o0.x = f2b(b2f(a0.x)*wa + b2f(b0.x)*wb); o0.y = f2b(b2f(a0.y)*wa + b2f(b0.y)*wb);
    o0.z = f2b(b2f(a0.z)*wa + b2f(b0.z)*wb); o0.w = f2b(b2f(a0.w)*wa + b2f(b0.w)*wb);
    o1.x = f2b(b2f(a1.x)*wa + b2f(b1.x)*wb); o1.y = f2b(b2f(a1.y)*wa + b2f(b1.y)*wb);
    o1.z = f2b(b2f(a1.z)*wa + b2f(b1.z)*wb); o1.w = f2b(b2f(a1.w)*wa + b2f(b1.w)*wb);
    *(ushort4*)&c0[i]   = o0;
    *(ushort4*)&c0[i+4] = o1;
}

// ---------------------------------------------------------------------------
// 8. attn_weights: q-tile 64, k-tile 64, loop all 16 h, NO atomics.
//    grid (32, 32, 2) = (q, k, b). Folded cc = M + log2(L); Q pre-scaled by
//    C2. Native v_exp_f32. K staged via global_load_lds. (Round-8 form —
//    the 2-phase dbuf variant blew VGPR to 248 and collapsed occupancy.)
// ---------------------------------------------------------------------------
__global__ __launch_bounds__(256) void k_attnw(
    const u16* __restrict__ qb, const u16* __restrict__ kb,
    const u16* __restrict__ maskb, const float* __restrict__ lstc,
    float* __restrict__ awout)
{
    int qs0 = blockIdx.x*64, ks0 = blockIdx.y*64, b = blockIdx.z;
    int t = threadIdx.x, lane = t & 63, wv_ = t >> 6;
    int quad = lane >> 4, lc = lane & 15;
    __shared__ u16 kt[64*64];
    __shared__ float scc[64];
    f32x4 T[4];
    #pragma unroll
    for (int j=0;j<4;j++) T[j] = (f32x4){0.f,0.f,0.f,0.f};

    int lsub = lane >> 3;
    int colsw = ((lane & 7) ^ lsub) << 3;
    int lrA = wv_*16 + lsub, lrB = wv_*16 + 8 + lsub;
    u16* kd0 = &kt[(wv_*16 + 0)*64];
    u16* kd1 = &kt[(wv_*16 + 8)*64];

    for (int h = 0; h < Hc; h++){
        __syncthreads();
        const u16* qp = qb + ((size_t)(b*Hc+h))*Sc*HDc;
        const u16* kp = kb + ((size_t)(b*Hc+h))*Sc*HDc;
        bf8 aq[2];
        #pragma unroll
        for (int ks = 0; ks < 2; ks++)
            aq[ks] = *(const bf8*)(qp + (size_t)(qs0 + wv_*16 + lc)*HDc + ks*32 + quad*8);
        gl16(kp + (size_t)(ks0 + lrA)*HDc + colsw, kd0);
        gl16(kp + (size_t)(ks0 + lrB)*HDc + colsw, kd1);
        if (t < 64)
            scc[t] = lstc[((size_t)(b*Hc+h))*Sc + qs0 + t];
        __syncthreads();
        f32x4 acc[4];
        #pragma unroll
        for (int j=0;j<4;j++) acc[j] = (f32x4){0.f,0.f,0.f,0.f};
        #pragma unroll
        for (int ks = 0; ks < 2; ks++){
            #pragma unroll
            for (int nb = 0; nb < 4; nb++){
                bf8 bb = *(const bf8*)swzc(kt, nb*16 + lc, ks*4 + quad);
                acc[nb] = MFMA(aq[ks], bb, acc[nb]);
            }
        }
        #pragma unroll
        for (int r = 0; r < 4; r++){
            int row = wv_*16 + quad*4 + r;
            float cv = scc[row];
            #pragma unroll
            for (int nb = 0; nb < 4; nb++)
                T[nb][r] += ex2(acc[nb][r] - cv);
        }
    }
    #pragma unroll
    for (int r = 0; r < 4; r++){
        int gq = qs0 + wv_*16 + quad*4 + r;
        #pragma unroll
        for (int nb = 0; nb < 4; nb++){
            int gk = ks0 + nb*16 + lc;
            float mk = b2f(maskb[(size_t)gq*Sc + gk]);   // mask*log2e
            awout[(size_t)b*Sc*Sc + (size_t)gq*Sc + gk]
                = T[nb][r]*ex2(mk)*(1.f/16.f);
        }
    }
}

// ---------------------------------------------------------------------------
// 10. output projection, MFMA. grid (8, NTILES). XOR-swizzled tiles staged
//     via global_load_lds (same mapping as k_qkv).
// ---------------------------------------------------------------------------
__global__ __launch_bounds__(256) void k_oproj(
    const u16* __restrict__ ctxb, const u16* __restrict__ woT,
    const int* __restrict__ perm, const int* __restrict__ tmeta,
    const u16* __restrict__ zbuf, float* __restrict__ opre)
{
    int meta = tmeta[blockIdx.y];
    if (meta < 0) return;
    int b = meta >> 1, m = meta & 1;
    const u16* W = woT + (size_t)m*Ec*Dc;
    int c0 = blockIdx.x*128;
    int t = threadIdx.x, lane = t & 63, wv_ = t >> 6;
    int quad = lane >> 4, lc = lane & 15;
    __shared__ u16 at[128*64];
    __shared__ u16 bt[128*64];
    __shared__ int sperm[128];
    if (t < 128) sperm[t] = perm[blockIdx.y*128 + t];
    f32x4 acc[2][8];
    #pragma unroll
    for (int i=0;i<2;i++)
        #pragma unroll
        for (int j=0;j<8;j++) acc[i][j] = (f32x4){0.f,0.f,0.f,0.f};
    __syncthreads();

    int colsw = ((lane & 7) ^ (lane >> 3)) << 3;
    const u16* ab[4]; const u16* bb[4];
    #pragma unroll
    for (int i = 0; i < 4; i++){
        int row = wv_*32 + i*8 + (lane >> 3);
        int s_ = sperm[row];
        ab[i] = (s_ >= 0) ? (ctxb + ((size_t)(b*Sc + s_))*Ec + colsw) : zbuf;
        bb[i] = W + (size_t)(c0 + row)*Ec + colsw;
    }

    for (int d0 = 0; d0 < Ec; d0 += 64){
        #pragma unroll
        for (int i = 0; i < 4; i++){
            gl16(ab[i] + d0, &at[(wv_*4 + i)*512]);
            gl16(bb[i] + d0, &bt[(wv_*4 + i)*512]);
        }
        __syncthreads();
        #pragma unroll
        for (int ks = 0; ks < 2; ks++){
            bf8 a0 = *(const bf8*)swzc(at, wv_*32 + lc,      ks*4 + quad);
            bf8 a1 = *(const bf8*)swzc(at, wv_*32 + 16 + lc, ks*4 + quad);
            #pragma unroll
            for (int nb = 0; nb < 8; nb++){
                bf8 bb2 = *(const bf8*)swzc(bt, nb*16 + lc, ks*4 + quad);
                acc[0][nb] = MFMA(a0, bb2, acc[0][nb]);
                acc[1][nb] = MFMA(a1, bb2, acc[1][nb]);
            }
        }
        __syncthreads();
    }
    #pragma unroll
    for (int mb = 0; mb < 2; mb++){
        #pragma unroll
        for (int r = 0; r < 4; r++){
            int row = wv_*32 + mb*16 + quad*4 + r;
            int s_ = sperm[row];
            if (s_ < 0) continue;
            #pragma unroll
            for (int nb = 0; nb < 8; nb++){
                int col = c0 + nb*16 + lc;
                opre[((size_t)(b*Sc + s_))*Dc + col] = acc[mb][nb][r];
            }
        }
    }
}

// ---------------------------------------------------------------------------
// 11. final RMSNorm over D -> out
// ---------------------------------------------------------------------------
__global__ __launch_bounds__(256) void k_onorm(
    const float* __restrict__ opre, const float* __restrict__ anw,
    const int* __restrict__ mod, float* __restrict__ out)
{
    int row = blockIdx.x;
    int m = mod[row];
    int t = threadIdx.x;
    float val[4];
    float ss = 0.f;
    #pragma unroll
    for (int j=0;j<4;j++){
        val[j] = opre[(size_t)row*Dc + t + 256*j];
        ss += val[j]*val[j];
    }
    #pragma unroll
    for (int o=32;o>0;o>>=1) ss += __shfl_xor(ss, o, 64);
    __shared__ float red[4];
    int wid = t>>6, lane = t&63;
    if (lane==0) red[wid]=ss;
    __syncthreads();
    float tot = red[0]+red[1]+red[2]+red[3];
    float rms = rsqrtf(tot*(1.f/1024.f) + EPSc);
    #pragma unroll
    for (int j=0;j<4;j++)
        out[(size_t)row*Dc + t + 256*j] = val[j]*rms*anw[m*Dc + t + 256*j];
}

// ---------------------------------------------------------------------------
extern "C" void kernel_launch(void* const* d_in, const int* in_sizes, int n_in,
                              void* d_out, int out_size, void* d_ws, size_t ws_size,
                              hipStream_t stream)
{
    const float* x    = (const float*)d_in[0];
    const float* mask = (const float*)d_in[1];
    const int*   mod  = (const int*)  d_in[2];
    const float* Wq   = (const float*)d_in[3];
    const float* Wk   = (const float*)d_in[4];
    const float* Wv   = (const float*)d_in[5];
    const float* Wo   = (const float*)d_in[6];
    const float* qnw  = (const float*)d_in[7];
    const float* knw  = (const float*)d_in[8];
    const float* anw  = (const float*)d_in[9];

    float* out   = (float*)d_out;                 // [B,S,D]
    float* awout = out + (size_t)Bc*Sc*Dc;        // [B,S,S]

    float* ws = (float*)d_ws;
    u16* qb    = (u16*)(ws + 0);
    u16* kb    = (u16*)(ws + 2097152);
    u16* vb    = (u16*)(ws + 4194304);   // dead after k_vt -> ctx partial 1
    u16* xb    = (u16*)(ws + 6291456);   // dead after k_qkv -> ctx partial 0
    u16* ctx0  = xb;
    u16* ctx1  = vb;
    u16* vtb   = (u16*)(ws + 8388608);
    u16* wqT   = (u16*)(ws + 10485760);
    u16* wkT   = (u16*)(ws + 11534336);
    u16* wvT   = (u16*)(ws + 12582912);
    u16* woT   = (u16*)(ws + 13631488);
    float* lstc= ws + 14680064;          // M + log2(L), 65536
    float* pm  = ws + 14811136;          // per-half m, 2*65536
    float* pl  = pm + 131072;            // per-half l, 2*65536
    float* w0  = ws + 15073280;          // combine weights, 65536 each
    float* w1  = w0 + 65536;
    u16* maskb = (u16*)(ws + 15335424);  // mask*log2e, bf16
    int* perm  = (int*)(ws + 17432576);
    int* tmeta = perm + NTILES*TILE_R;
    u16* zbuf  = (u16*)(tmeta + NTILES + 28);   // 4KB zero scratch (aligned)
    float* opre = ws;                    // aliases qb+kb (dead by then)

    k_perm  <<<dim3(1),            256, 0, stream>>>(mod, perm, tmeta, zbuf);
    k_prep  <<<dim3(8192),         256, 0, stream>>>(x, mask, xb, maskb);
    k_tcvt  <<<dim3(32,32,8),      256, 0, stream>>>(Wq, Wk, Wv, Wo, wqT, wkT, wvT, woT);
    k_qkv   <<<dim3(8,NTILES,3),   256, 0, stream>>>(xb, wqT, wkT, wvT, perm, tmeta,
                                                     qnw, knw, zbuf, qb, kb, vb);
    k_vt    <<<dim3(32,32),        256, 0, stream>>>(vb, vtb);
    k_flash <<<dim3(32,16,4),      256, 0, stream>>>(qb, kb, vtb, maskb, pm, pl, ctx0, ctx1);
    k_merge <<<dim3(256),          256, 0, stream>>>(pm, pl, lstc, w0, w1);
    k_attnw <<<dim3(32,32,2),      256, 0, stream>>>(qb, kb, maskb, lstc, awout);
    k_addc  <<<dim3(2048),         256, 0, stream>>>(ctx0, ctx1, w0, w1);
    k_oproj <<<dim3(8,NTILES),     256, 0, stream>>>(ctx0, woT, perm, tmeta, zbuf, opre);
    k_onorm <<<dim3(4096),         256, 0, stream>>>(opre, anw, mod, out);
}

// Round 11
// 338.569 us; speedup vs baseline: 1.1440x; 1.0211x over previous
//
#include <hip/hip_runtime.h>
#include <cstdint>

#define Bc  2
#define Sc  2048
#define Dc  1024
#define Ec  1024
#define Hc  16
#define HDc 64
#define TTc (Bc*Sc)
#define TILE_R 128
#define NTILES 36
#define EPSc 1e-5f
#define LOG2E 1.44269504f
#define C2    (0.125f*LOG2E)

typedef unsigned short u16;
using bf8   = __attribute__((ext_vector_type(8))) short;
using f32x4 = __attribute__((ext_vector_type(4))) float;
#define MFMA(a,b,c) __builtin_amdgcn_mfma_f32_16x16x32_bf16(a,b,c,0,0,0)

static __device__ __forceinline__ u16 f2b(float f){
    return (u16)((__float_as_uint(f) + 0x8000u) >> 16);
}
static __device__ __forceinline__ float b2f(u16 s){
    return __uint_as_float(((unsigned)s) << 16);
}
// raw v_exp_f32 (2^x): inputs here are <= ~8; underflow flushes to 0 which is
// exactly the wanted semantics. Avoids OCML's multi-instruction wrapper.
static __device__ __forceinline__ float ex2(float x){
    return __builtin_amdgcn_exp2f(x);
}
// pack two f32 -> one dword of 2 bf16 (low = a, high = b), single VALU op
static __device__ __forceinline__ unsigned cvtpk(float a, float b){
    unsigned r;
    asm("v_cvt_pk_bf16_f32 %0, %1, %2" : "=v"(r) : "v"(a), "v"(b));
    return r;
}
union bfpack { unsigned u[4]; bf8 v; };
// 3-input max; clang fuses to v_max3_f32
static __device__ __forceinline__ float max3f(float a, float b, float c){
    return fmaxf(fmaxf(a, b), c);
}
// XOR-swizzled LDS addressing: tiles are [R][64] u16, 8-u16 (16B) groups,
// group index col8 swizzled by row&7 -> fragment ds_read_b128 is
// bank-conflict-free.
static __device__ __forceinline__ u16* swz(u16* base, int row, int col8){
    return base + row*64 + ((col8 ^ (row & 7)) << 3);
}
static __device__ __forceinline__ const u16* swzc(const u16* base, int row, int col8){
    return base + row*64 + ((col8 ^ (row & 7)) << 3);
}
// async global->LDS, 16B per lane. LDS dest = wave-uniform base + lane*16
// (linear); the swizzle is applied by inverse-permuting the per-lane global
// source address (rule: linear dest + inv-swz source + swz read).
typedef const __attribute__((address_space(1))) void* gp1;
typedef __attribute__((address_space(3))) void* lp3;
static __device__ __forceinline__ void gl16(const void* g, void* l){
    __builtin_amdgcn_global_load_lds((gp1)g, (lp3)l, 16, 0, 0);
}
// inverse of the k_flash pi row permutation (pi: pr4=g2, pr3=g4, pr2=g3)
static __device__ __forceinline__ int pinv(int lr){
    return (lr & 0x23) | ((lr & 0x10) >> 2) | ((lr & 0x0C) << 1);
}

// ---------------------------------------------------------------------------
// 1. modality-sorted token permutation, 128-padded segments per (b,m).
//    Also zeroes the 4KB zbuf used by gload_lds staging for padding rows.
// ---------------------------------------------------------------------------
__global__ void k_perm(const int* __restrict__ mod, int* __restrict__ perm,
                       int* __restrict__ tmeta, u16* __restrict__ zbuf)
{
    __shared__ int cnt[4], segstart[4];
    int t = threadIdx.x;
    for (int i = t; i < 2048; i += 256) zbuf[i] = 0;
    if (t < 4) cnt[t] = 0;
    __syncthreads();
    for (int i = t; i < TTc; i += 256){
        int b = i >> 11; int m = mod[i];
        atomicAdd(&cnt[b*2+m], 1);
    }
    __syncthreads();
    if (t == 0){
        int off = 0;
        for (int i = 0; i < 4; i++){
            segstart[i] = off;
            int pad = ((cnt[i] + TILE_R - 1)/TILE_R)*TILE_R;
            for (int tt = off/TILE_R; tt < (off+pad)/TILE_R; tt++) tmeta[tt] = i;
            off += pad;
        }
        for (int tt = off/TILE_R; tt < NTILES; tt++) tmeta[tt] = -1;
    }
    __syncthreads();
    if (t < 4) cnt[t] = 0;
    for (int i = t; i < NTILES*TILE_R; i += 256) perm[i] = -1;
    __syncthreads();
    for (int i = t; i < TTc; i += 256){
        int b = i >> 11, s = i & 2047; int m = mod[i];
        int r = atomicAdd(&cnt[b*2+m], 1);
        perm[segstart[b*2+m] + r] = s;
    }
}

// ---------------------------------------------------------------------------
// 2. fused fp32->bf16 conversion: x (plain) + mask (scaled by LOG2E).
//    grid 8192: blocks [0,4096) -> x, [4096,8192) -> mask.
// ---------------------------------------------------------------------------
__global__ __launch_bounds__(256) void k_prep(
    const float* __restrict__ x, const float* __restrict__ mask,
    u16* __restrict__ xb, u16* __restrict__ maskb)
{
    int bid = blockIdx.x;
    if (bid < 4096){
        int i = (bid*256 + threadIdx.x)*4;
        float4 v = *(const float4*)&x[i];
        ushort4 o;
        o.x = f2b(v.x); o.y = f2b(v.y); o.z = f2b(v.z); o.w = f2b(v.w);
        *(ushort4*)&xb[i] = o;
    } else {
        int i = ((bid-4096)*256 + threadIdx.x)*4;
        float4 v = *(const float4*)&mask[i];
        ushort4 o;
        o.x = f2b(v.x*LOG2E); o.y = f2b(v.y*LOG2E);
        o.z = f2b(v.z*LOG2E); o.w = f2b(v.w*LOG2E);
        *(ushort4*)&maskb[i] = o;
    }
}

// ---------------------------------------------------------------------------
// 3. transpose+convert all four weights in one launch; grid (32,32,8)
// ---------------------------------------------------------------------------
__global__ __launch_bounds__(256) void k_tcvt(
    const float* __restrict__ s0, const float* __restrict__ s1,
    const float* __restrict__ s2, const float* __restrict__ s3,
    u16* __restrict__ d0, u16* __restrict__ d1,
    u16* __restrict__ d2, u16* __restrict__ d3)
{
    int wsel = blockIdx.z >> 1, m = blockIdx.z & 1;
    const float* src = (wsel==0?s0:wsel==1?s1:wsel==2?s2:s3) + (size_t)m*1048576;
    u16*       dst = (wsel==0?d0:wsel==1?d1:wsel==2?d2:d3) + (size_t)m*1048576;
    __shared__ float sh[32][33];
    int t = threadIdx.x;
    int i0 = blockIdx.x*32, j0 = blockIdx.y*32;
    {
        int i = t >> 3, j4 = (t & 7)*4;
        *(float4*)&sh[i][j4] = *(const float4*)&src[(size_t)(i0+i)*1024 + j0 + j4];
    }
    __syncthreads();
    {
        int j = t >> 3, i4 = (t & 7)*4;
        ushort4 o;
        o.x = f2b(sh[i4+0][j]); o.y = f2b(sh[i4+1][j]);
        o.z = f2b(sh[i4+2][j]); o.w = f2b(sh[i4+3][j]);
        *(ushort4*)&dst[(size_t)(j0+j)*1024 + i0 + i4] = o;
    }
}

// ---------------------------------------------------------------------------
// 4. QKV projection, MFMA, fused per-head RMSNorm for Q and K.
//    grid (8, NTILES, 3). LDS tiles XOR-swizzled [128][64], staged via
//    global_load_lds (linear dest, inverse-swizzled per-lane source).
//    Q folded with C2 = 0.125*log2e.
// ---------------------------------------------------------------------------
__global__ __launch_bounds__(256) void k_qkv(
    const u16* __restrict__ xb, const u16* __restrict__ wqT,
    const u16* __restrict__ wkT, const u16* __restrict__ wvT,
    const int* __restrict__ perm, const int* __restrict__ tmeta,
    const float* __restrict__ qnw, const float* __restrict__ knw,
    const u16* __restrict__ zbuf,
    u16* __restrict__ qb, u16* __restrict__ kb, u16* __restrict__ vb)
{
    int meta = tmeta[blockIdx.y];
    if (meta < 0) return;
    int b = meta >> 1, m = meta & 1;
    const u16* W = (blockIdx.z==0 ? wqT : (blockIdx.z==1 ? wkT : wvT)) + (size_t)m*Ec*Dc;
    u16* outp    = (blockIdx.z==0 ? qb  : (blockIdx.z==1 ? kb  : vb));
    int c0 = blockIdx.x*128;
    int t = threadIdx.x, lane = t & 63, wv_ = t >> 6;
    int quad = lane >> 4, lc = lane & 15;

    __shared__ u16 at[128*64];
    __shared__ u16 bt[128*64];
    __shared__ int sperm[128];
    if (t < 128) sperm[t] = perm[blockIdx.y*128 + t];
    f32x4 acc[2][8];
    #pragma unroll
    for (int i=0;i<2;i++)
        #pragma unroll
        for (int j=0;j<8;j++) acc[i][j] = (f32x4){0.f,0.f,0.f,0.f};
    __syncthreads();

    // staging sources: wave w instr i lane l covers LDS row w*32+i*8+(l>>3),
    // stored group l&7 -> true col8 = (l&7)^(l>>3) (row&7 == l>>3).
    int colsw = ((lane & 7) ^ (lane >> 3)) << 3;
    const u16* ab[4]; const u16* bb[4];
    #pragma unroll
    for (int i = 0; i < 4; i++){
        int row = wv_*32 + i*8 + (lane >> 3);
        int s_ = sperm[row];
        ab[i] = (s_ >= 0) ? (xb + ((size_t)(b*Sc + s_))*Dc + colsw) : zbuf;
        bb[i] = W + (size_t)(c0 + row)*Dc + colsw;
    }

    for (int d0 = 0; d0 < Dc; d0 += 64){
        #pragma unroll
        for (int i = 0; i < 4; i++){
            gl16(ab[i] + d0, &at[(wv_*4 + i)*512]);
            gl16(bb[i] + d0, &bt[(wv_*4 + i)*512]);
        }
        __syncthreads();
        #pragma unroll
        for (int ks = 0; ks < 2; ks++){
            bf8 a0 = *(const bf8*)swzc(at, wv_*32 + lc,      ks*4 + quad);
            bf8 a1 = *(const bf8*)swzc(at, wv_*32 + 16 + lc, ks*4 + quad);
            #pragma unroll
            for (int nb = 0; nb < 8; nb++){
                bf8 bb2 = *(const bf8*)swzc(bt, nb*16 + lc, ks*4 + quad);
                acc[0][nb] = MFMA(a0, bb2, acc[0][nb]);
                acc[1][nb] = MFMA(a1, bb2, acc[1][nb]);
            }
        }
        __syncthreads();
    }

    if (blockIdx.z < 2){
        const float* nw = (blockIdx.z==0 ? qnw : knw) + m*HDc;
        float cs = (blockIdx.z==0) ? C2 : 1.f;   // fold score scale into Q
        float w0 = nw[lc]*cs, w1 = nw[16+lc]*cs, w2 = nw[32+lc]*cs, w3 = nw[48+lc]*cs;
        #pragma unroll
        for (int mb = 0; mb < 2; mb++){
            #pragma unroll
            for (int r = 0; r < 4; r++){
                #pragma unroll
                for (int g = 0; g < 2; g++){
                    float ss = 0.f;
                    #pragma unroll
                    for (int j = 0; j < 4; j++){
                        float v2 = acc[mb][g*4+j][r];
                        ss += v2*v2;
                    }
                    ss += __shfl_xor(ss, 1, 64);
                    ss += __shfl_xor(ss, 2, 64);
                    ss += __shfl_xor(ss, 4, 64);
                    ss += __shfl_xor(ss, 8, 64);
                    float rs = rsqrtf(ss*(1.f/64.f) + EPSc);
                    acc[mb][g*4+0][r] *= rs*w0;
                    acc[mb][g*4+1][r] *= rs*w1;
                    acc[mb][g*4+2][r] *= rs*w2;
                    acc[mb][g*4+3][r] *= rs*w3;
                }
            }
        }
    }

    int h0 = c0 >> 6;
    #pragma unroll
    for (int mb = 0; mb < 2; mb++){
        #pragma unroll
        for (int r = 0; r < 4; r++){
            int row = wv_*32 + mb*16 + quad*4 + r;
            int s_ = sperm[row];
            if (s_ < 0) continue;
            #pragma unroll
            for (int nb = 0; nb < 8; nb++){
                int col = nb*16 + lc;
                int h = h0 + (col >> 6), hd = col & 63;
                outp[(((size_t)(b*Hc + h))*Sc + s_)*HDc + hd] = f2b(acc[mb][nb][r]);
            }
        }
    }
}

// ---------------------------------------------------------------------------
// 6. V transpose via LDS tiles: vb [BH][S][HD] -> vtb [BH][HD][S]
// ---------------------------------------------------------------------------
__global__ __launch_bounds__(256) void k_vt(const u16* __restrict__ vb,
                                            u16* __restrict__ vtb)
{
    __shared__ u16 sh[64][72];
    int t = threadIdx.x;
    int s0 = blockIdx.x*64, bh = blockIdx.y;
    {
        int rr = t >> 2, cc = (t & 3)*16;
        const u16* src = vb + ((size_t)bh*Sc + s0 + rr)*HDc + cc;
        *(uint4*)&sh[rr][cc]   = *(const uint4*)(src);
        *(uint4*)&sh[rr][cc+8] = *(const uint4*)(src+8);
    }
    __syncthreads();
    {
        int hd = t >> 2, sc = (t & 3)*16;
        u16 tmp[16];
        #pragma unroll
        for (int j = 0; j < 16; j++) tmp[j] = sh[sc+j][hd];
        u16* dst = vtb + ((size_t)bh*HDc + hd)*Sc + s0 + sc;
        *(uint4*)(dst)   = *(const uint4*)&tmp[0];
        *(uint4*)(dst+8) = *(const uint4*)&tmp[8];
    }
}

// ---------------------------------------------------------------------------
// 9. flash PV with ONLINE softmax + defer-max (THR=8), FULL K per block:
//    grid (32, 16, 2): z = b. 1024 blocks = 4 blocks/CU resident.
//    No split-K: block normalizes ctx by its own complete row-sum and
//    writes lstc = rm + log2(l) directly -> k_merge/k_addc deleted.
//    2-phase double-buffered staging (gl16 K/V + mask regs, 1 barrier/tile).
//    Swapped QK^T + pi-permuted K keeps P in registers in exact PV A-frag
//    layout. Row-sum l via MFMA ones-operand (racc rows == oacc rows).
// ---------------------------------------------------------------------------
__global__ __launch_bounds__(256) void k_flash(
    const u16* __restrict__ qb, const u16* __restrict__ kb,
    const u16* __restrict__ vtb, const u16* __restrict__ maskb,
    float* __restrict__ lstc, u16* __restrict__ c0)
{
    int qs0 = blockIdx.x*64, h = blockIdx.y;
    int b = blockIdx.z;
    int t = threadIdx.x, lane = t & 63, wv_ = t >> 6;
    int quad = lane >> 4, lc = lane & 15;
    __shared__ u16 kt[2][64*64];
    __shared__ u16 vt[2][64*64];
    const u16* qp  = qb  + ((size_t)(b*Hc+h))*Sc*HDc;
    const u16* kp  = kb  + ((size_t)(b*Hc+h))*Sc*HDc;
    const u16* vtp = vtb + ((size_t)(b*Hc+h))*HDc*Sc;
    const u16* mq  = maskb + (size_t)(qs0 + wv_*16 + lc)*Sc;  // this lane's q-row
    bf8 aq[2];
    #pragma unroll
    for (int ks = 0; ks < 2; ks++)
        aq[ks] = *(const bf8*)(qp + (size_t)(qs0 + wv_*16 + lc)*HDc + ks*32 + quad*8);
    // all-ones B fragment for MFMA row sums
    bfpack onep; onep.u[0] = onep.u[1] = onep.u[2] = onep.u[3] = 0x3F803F80u;
    bf8 ones = onep.v;
    // online stats: rm per-lane for q-row lc (quad-replicated); l via racc
    float rm = -1.0e30f;
    f32x4 racc = (f32x4){0.f,0.f,0.f,0.f};
    f32x4 oacc[4];
    #pragma unroll
    for (int j=0;j<4;j++) oacc[j] = (f32x4){0.f,0.f,0.f,0.f};

    // gl16 staging geometry (per wave: rows w*16..w*16+15 of each tile)
    int lsub = lane >> 3;
    int colsw = ((lane & 7) ^ lsub) << 3;
    int lrA = wv_*16 + lsub, lrB = wv_*16 + 8 + lsub;
    const u16* kg0 = kp + (size_t)pinv(lrA)*HDc + colsw;
    const u16* kg1 = kp + (size_t)pinv(lrB)*HDc + colsw;
    const u16* vg0 = vtp + (size_t)lrA*Sc + colsw;
    const u16* vg1 = vtp + (size_t)lrB*Sc + colsw;
    int kdo0 = (wv_*16 + 0)*64, kdo1 = (wv_*16 + 8)*64;

    // prologue: stage tile 0 into buffer 0, prefetch its mask
    gl16(kg0, &kt[0][kdo0]);
    gl16(kg1, &kt[0][kdo1]);
    gl16(vg0, &vt[0][kdo0]);
    gl16(vg1, &vt[0][kdo1]);
    ushort4 mv[2][2];
    #pragma unroll
    for (int a1 = 0; a1 < 2; a1++)
        #pragma unroll
        for (int b1 = 0; b1 < 2; b1++)
            mv[a1][b1] = *(const ushort4*)(mq + a1*32 + quad*8 + b1*4);
    __syncthreads();   // drains prologue staging -> buffer 0 ready

    int cur = 0;
    for (int kc = 0; kc < Sc; kc += 64){
        // stage NEXT tile into the shadow buffer (clamped on last iter;
        // redundant loads land in the unused buffer, drained by last barrier)
        int nxt = (kc + 64 < Sc) ? kc + 64 : kc;
        gl16(kg0 + (size_t)nxt*HDc, &kt[cur^1][kdo0]);
        gl16(kg1 + (size_t)nxt*HDc, &kt[cur^1][kdo1]);
        gl16(vg0 + nxt, &vt[cur^1][kdo0]);
        gl16(vg1 + nxt, &vt[cur^1][kdo1]);
        ushort4 mvn[2][2];
        #pragma unroll
        for (int a1 = 0; a1 < 2; a1++)
            #pragma unroll
            for (int b1 = 0; b1 < 2; b1++)
                mvn[a1][b1] = *(const ushort4*)(mq + nxt + a1*32 + quad*8 + b1*4);

        const u16* ktc = kt[cur];
        const u16* vtc = vt[cur];
        // S^T = K * Q^T (Q pre-scaled by C2)
        f32x4 acc[4];
        #pragma unroll
        for (int j=0;j<4;j++) acc[j] = (f32x4){0.f,0.f,0.f,0.f};
        #pragma unroll
        for (int ks = 0; ks < 2; ks++){
            #pragma unroll
            for (int nb = 0; nb < 4; nb++){
                bf8 ak = *(const bf8*)swzc(ktc, nb*16 + lc, ks*4 + quad);
                acc[nb] = MFMA(ak, aq[ks], acc[nb]);
            }
        }
        // scores + mask; per-lane max via max3 tree
        float svv[4][4];
        #pragma unroll
        for (int a1 = 0; a1 < 2; a1++){
            #pragma unroll
            for (int b1 = 0; b1 < 2; b1++){
                int nb = 2*a1 + b1;
                #pragma unroll
                for (int r = 0; r < 4; r++){
                    u16 mraw = (r==0?mv[a1][b1].x:r==1?mv[a1][b1].y:
                                r==2?mv[a1][b1].z:mv[a1][b1].w);
                    svv[nb][r] = acc[nb][r] + b2f(mraw);
                }
            }
        }
        float m0_ = max3f(svv[0][0], svv[0][1], svv[0][2]);
        float m1_ = max3f(svv[0][3], svv[1][0], svv[1][1]);
        float m2_ = max3f(svv[1][2], svv[1][3], svv[2][0]);
        float m3_ = max3f(svv[2][1], svv[2][2], svv[2][3]);
        float m4_ = max3f(svv[3][0], svv[3][1], svv[3][2]);
        float mxl = fmaxf(max3f(m0_, m1_, m2_), max3f(m3_, m4_, svv[3][3]));
        // defer-max: only reduce/rescale when some lane grew past rm + 8
        if (__any(mxl > rm + 8.f)){
            float mx = fmaxf(mxl, __shfl_xor(mxl, 16, 64));
            mx = fmaxf(mx, __shfl_xor(mx, 32, 64));
            float nm = fmaxf(rm, mx);
            float fac = ex2(rm - nm);
            rm = nm;
            float f0 = __shfl(fac, quad*4+0, 64);
            float f1 = __shfl(fac, quad*4+1, 64);
            float f2 = __shfl(fac, quad*4+2, 64);
            float f3 = __shfl(fac, quad*4+3, 64);
            racc[0] *= f0; racc[1] *= f1; racc[2] *= f2; racc[3] *= f3;
            #pragma unroll
            for (int nb = 0; nb < 4; nb++){
                oacc[nb][0] *= f0; oacc[nb][1] *= f1;
                oacc[nb][2] *= f2; oacc[nb][3] *= f3;
            }
        }
        // P (bounded by 2^8) packed via cvt_pk straight into PV A-fragments;
        // row sums accumulated on the matrix pipe via the ones fragment.
        #pragma unroll
        for (int a1 = 0; a1 < 2; a1++){
            bfpack pk;
            pk.u[0] = cvtpk(ex2(svv[2*a1][0] - rm),   ex2(svv[2*a1][1] - rm));
            pk.u[1] = cvtpk(ex2(svv[2*a1][2] - rm),   ex2(svv[2*a1][3] - rm));
            pk.u[2] = cvtpk(ex2(svv[2*a1+1][0] - rm), ex2(svv[2*a1+1][1] - rm));
            pk.u[3] = cvtpk(ex2(svv[2*a1+1][2] - rm), ex2(svv[2*a1+1][3] - rm));
            bf8 ap = pk.v;
            racc = MFMA(ap, ones, racc);
            #pragma unroll
            for (int nb2 = 0; nb2 < 4; nb2++){
                bf8 bv = *(const bf8*)swzc(vtc, nb2*16 + lc, a1*4 + quad);
                oacc[nb2] = MFMA(ap, bv, oacc[nb2]);
            }
        }
        __syncthreads();   // one barrier/tile: drains shadow staging + ds_reads
        #pragma unroll
        for (int a1 = 0; a1 < 2; a1++)
            #pragma unroll
            for (int b1 = 0; b1 < 2; b1++)
                mv[a1][b1] = mvn[a1][b1];
        cur ^= 1;
    }
    // lstc = rm + log2(l): rm is quad-replicated per lc, so shfl from lanes
    // 0..15 (always valid) pairs row quad*4+r's rm with racc[r] on lc==0.
    float rmr[4];
    #pragma unroll
    for (int r = 0; r < 4; r++) rmr[r] = __shfl(rm, quad*4 + r, 64);
    size_t sbase = ((size_t)(b*Hc+h))*Sc + qs0 + wv_*16;
    if (lc == 0){
        #pragma unroll
        for (int r = 0; r < 4; r++)
            lstc[sbase + quad*4 + r] = rmr[r] + log2f(racc[r]);
    }
    // ctx normalized by the full row-sum (racc rows match oacc rows)
    #pragma unroll
    for (int r = 0; r < 4; r++){
        float ir = 1.f/racc[r];
        int tok = qs0 + wv_*16 + quad*4 + r;
        #pragma unroll
        for (int nb = 0; nb < 4; nb++){
            int hd = nb*16 + lc;
            c0[((size_t)(b*Sc + tok))*Ec + h*HDc + hd] = f2b(oacc[nb][r]*ir);
        }
    }
}

// ---------------------------------------------------------------------------
// 8. attn_weights: q-tile 64, k-tile 64, loop all 16 h, NO atomics.
//    grid (32, 32, 2) = (q, k, b). Folded cc = lstc = rm + log2(l); Q
//    pre-scaled by C2. Native v_exp_f32. K staged via global_load_lds.
// ---------------------------------------------------------------------------
__global__ __launch_bounds__(256) void k_attnw(
    const u16* __restrict__ qb, const u16* __restrict__ kb,
    const u16* __restrict__ maskb, const float* __restrict__ lstc,
    float* __restrict__ awout)
{
    int qs0 = blockIdx.x*64, ks0 = blockIdx.y*64, b = blockIdx.z;
    int t = threadIdx.x, lane = t & 63, wv_ = t >> 6;
    int quad = lane >> 4, lc = lane & 15;
    __shared__ u16 kt[64*64];
    __shared__ float scc[64];
    f32x4 T[4];
    #pragma unroll
    for (int j=0;j<4;j++) T[j] = (f32x4){0.f,0.f,0.f,0.f};

    int lsub = lane >> 3;
    int colsw = ((lane & 7) ^ lsub) << 3;
    int lrA = wv_*16 + lsub, lrB = wv_*16 + 8 + lsub;
    u16* kd0 = &kt[(wv_*16 + 0)*64];
    u16* kd1 = &kt[(wv_*16 + 8)*64];

    for (int h = 0; h < Hc; h++){
        __syncthreads();
        const u16* qp = qb + ((size_t)(b*Hc+h))*Sc*HDc;
        const u16* kp = kb + ((size_t)(b*Hc+h))*Sc*HDc;
        bf8 aq[2];
        #pragma unroll
        for (int ks = 0; ks < 2; ks++)
            aq[ks] = *(const bf8*)(qp + (size_t)(qs0 + wv_*16 + lc)*HDc + ks*32 + quad*8);
        gl16(kp + (size_t)(ks0 + lrA)*HDc + colsw, kd0);
        gl16(kp + (size_t)(ks0 + lrB)*HDc + colsw, kd1);
        if (t < 64)
            scc[t] = lstc[((size_t)(b*Hc+h))*Sc + qs0 + t];
        __syncthreads();
        f32x4 acc[4];
        #pragma unroll
        for (int j=0;j<4;j++) acc[j] = (f32x4){0.f,0.f,0.f,0.f};
        #pragma unroll
        for (int ks = 0; ks < 2; ks++){
            #pragma unroll
            for (int nb = 0; nb < 4; nb++){
                bf8 bb = *(const bf8*)swzc(kt, nb*16 + lc, ks*4 + quad);
                acc[nb] = MFMA(aq[ks], bb, acc[nb]);
            }
        }
        #pragma unroll
        for (int r = 0; r < 4; r++){
            int row = wv_*16 + quad*4 + r;
            float cv = scc[row];
            #pragma unroll
            for (int nb = 0; nb < 4; nb++)
                T[nb][r] += ex2(acc[nb][r] - cv);
        }
    }
    #pragma unroll
    for (int r = 0; r < 4; r++){
        int gq = qs0 + wv_*16 + quad*4 + r;
        #pragma unroll
        for (int nb = 0; nb < 4; nb++){
            int gk = ks0 + nb*16 + lc;
            float mk = b2f(maskb[(size_t)gq*Sc + gk]);   // mask*log2e
            awout[(size_t)b*Sc*Sc + (size_t)gq*Sc + gk]
                = T[nb][r]*ex2(mk)*(1.f/16.f);
        }
    }
}

// ---------------------------------------------------------------------------
// 10. output projection, MFMA. grid (8, NTILES). XOR-swizzled tiles staged
//     via global_load_lds (same mapping as k_qkv).
// ---------------------------------------------------------------------------
__global__ __launch_bounds__(256) void k_oproj(
    const u16* __restrict__ ctxb, const u16* __restrict__ woT,
    const int* __restrict__ perm, const int* __restrict__ tmeta,
    const u16* __restrict__ zbuf, float* __restrict__ opre)
{
    int meta = tmeta[blockIdx.y];
    if (meta < 0) return;
    int b = meta >> 1, m = meta & 1;
    const u16* W = woT + (size_t)m*Ec*Dc;
    int c0 = blockIdx.x*128;
    int t = threadIdx.x, lane = t & 63, wv_ = t >> 6;
    int quad = lane >> 4, lc = lane & 15;
    __shared__ u16 at[128*64];
    __shared__ u16 bt[128*64];
    __shared__ int sperm[128];
    if (t < 128) sperm[t] = perm[blockIdx.y*128 + t];
    f32x4 acc[2][8];
    #pragma unroll
    for (int i=0;i<2;i++)
        #pragma unroll
        for (int j=0;j<8;j++) acc[i][j] = (f32x4){0.f,0.f,0.f,0.f};
    __syncthreads();

    int colsw = ((lane & 7) ^ (lane >> 3)) << 3;
    const u16* ab[4]; const u16* bb[4];
    #pragma unroll
    for (int i = 0; i < 4; i++){
        int row = wv_*32 + i*8 + (lane >> 3);
        int s_ = sperm[row];
        ab[i] = (s_ >= 0) ? (ctxb + ((size_t)(b*Sc + s_))*Ec + colsw) : zbuf;
        bb[i] = W + (size_t)(c0 + row)*Ec + colsw;
    }

    for (int d0 = 0; d0 < Ec; d0 += 64){
        #pragma unroll
        for (int i = 0; i < 4; i++){
            gl16(ab[i] + d0, &at[(wv_*4 + i)*512]);
            gl16(bb[i] + d0, &bt[(wv_*4 + i)*512]);
        }
        __syncthreads();
        #pragma unroll
        for (int ks = 0; ks < 2; ks++){
            bf8 a0 = *(const bf8*)swzc(at, wv_*32 + lc,      ks*4 + quad);
            bf8 a1 = *(const bf8*)swzc(at, wv_*32 + 16 + lc, ks*4 + quad);
            #pragma unroll
            for (int nb = 0; nb < 8; nb++){
                bf8 bb2 = *(const bf8*)swzc(bt, nb*16 + lc, ks*4 + quad);
                acc[0][nb] = MFMA(a0, bb2, acc[0][nb]);
                acc[1][nb] = MFMA(a1, bb2, acc[1][nb]);
            }
        }
        __syncthreads();
    }
    #pragma unroll
    for (int mb = 0; mb < 2; mb++){
        #pragma unroll
        for (int r = 0; r < 4; r++){
            int row = wv_*32 + mb*16 + quad*4 + r;
            int s_ = sperm[row];
            if (s_ < 0) continue;
            #pragma unroll
            for (int nb = 0; nb < 8; nb++){
                int col = c0 + nb*16 + lc;
                opre[((size_t)(b*Sc + s_))*Dc + col] = acc[mb][nb][r];
            }
        }
    }
}

// ---------------------------------------------------------------------------
// 11. final RMSNorm over D -> out
// ---------------------------------------------------------------------------
__global__ __launch_bounds__(256) void k_onorm(
    const float* __restrict__ opre, const float* __restrict__ anw,
    const int* __restrict__ mod, float* __restrict__ out)
{
    int row = blockIdx.x;
    int m = mod[row];
    int t = threadIdx.x;
    float val[4];
    float ss = 0.f;
    #pragma unroll
    for (int j=0;j<4;j++){
        val[j] = opre[(size_t)row*Dc + t + 256*j];
        ss += val[j]*val[j];
    }
    #pragma unroll
    for (int o=32;o>0;o>>=1) ss += __shfl_xor(ss, o, 64);
    __shared__ float red[4];
    int wid = t>>6, lane = t&63;
    if (lane==0) red[wid]=ss;
    __syncthreads();
    float tot = red[0]+red[1]+red[2]+red[3];
    float rms = rsqrtf(tot*(1.f/1024.f) + EPSc);
    #pragma unroll
    for (int j=0;j<4;j++)
        out[(size_t)row*Dc + t + 256*j] = val[j]*rms*anw[m*Dc + t + 256*j];
}

// ---------------------------------------------------------------------------
extern "C" void kernel_launch(void* const* d_in, const int* in_sizes, int n_in,
                              void* d_out, int out_size, void* d_ws, size_t ws_size,
                              hipStream_t stream)
{
    const float* x    = (const float*)d_in[0];
    const float* mask = (const float*)d_in[1];
    const int*   mod  = (const int*)  d_in[2];
    const float* Wq   = (const float*)d_in[3];
    const float* Wk   = (const float*)d_in[4];
    const float* Wv   = (const float*)d_in[5];
    const float* Wo   = (const float*)d_in[6];
    const float* qnw  = (const float*)d_in[7];
    const float* knw  = (const float*)d_in[8];
    const float* anw  = (const float*)d_in[9];

    float* out   = (float*)d_out;                 // [B,S,D]
    float* awout = out + (size_t)Bc*Sc*Dc;        // [B,S,S]

    float* ws = (float*)d_ws;
    u16* qb    = (u16*)(ws + 0);
    u16* kb    = (u16*)(ws + 2097152);
    u16* vb    = (u16*)(ws + 4194304);   // dead after k_vt
    u16* xb    = (u16*)(ws + 6291456);   // dead after k_qkv -> ctx
    u16* ctx0  = xb;
    u16* vtb   = (u16*)(ws + 8388608);
    u16* wqT   = (u16*)(ws + 10485760);
    u16* wkT   = (u16*)(ws + 11534336);
    u16* wvT   = (u16*)(ws + 12582912);
    u16* woT   = (u16*)(ws + 13631488);
    float* lstc= ws + 14680064;          // rm + log2(l), 65536
    u16* maskb = (u16*)(ws + 15335424);  // mask*log2e, bf16
    int* perm  = (int*)(ws + 17432576);
    int* tmeta = perm + NTILES*TILE_R;
    u16* zbuf  = (u16*)(tmeta + NTILES + 28);   // 4KB zero scratch (aligned)
    float* opre = ws;                    // aliases qb+kb (dead by then)

    k_perm  <<<dim3(1),            256, 0, stream>>>(mod, perm, tmeta, zbuf);
    k_prep  <<<dim3(8192),         256, 0, stream>>>(x, mask, xb, maskb);
    k_tcvt  <<<dim3(32,32,8),      256, 0, stream>>>(Wq, Wk, Wv, Wo, wqT, wkT, wvT, woT);
    k_qkv   <<<dim3(8,NTILES,3),   256, 0, stream>>>(xb, wqT, wkT, wvT, perm, tmeta,
                                                     qnw, knw, zbuf, qb, kb, vb);
    k_vt    <<<dim3(32,32),        256, 0, stream>>>(vb, vtb);
    k_flash <<<dim3(32,16,2),      256, 0, stream>>>(qb, kb, vtb, maskb, lstc, ctx0);
    k_attnw <<<dim3(32,32,2),      256, 0, stream>>>(qb, kb, maskb, lstc, awout);
    k_oproj <<<dim3(8,NTILES),     256, 0, stream>>>(ctx0, woT, perm, tmeta, zbuf, opre);
    k_onorm <<<dim3(4096),         256, 0, stream>>>(opre, anw, mod, out);
}

// Round 12
// 337.549 us; speedup vs baseline: 1.1474x; 1.0030x over previous
//
#include <hip/hip_runtime.h>
#include <cstdint>

#define Bc  2
#define Sc  2048
#define Dc  1024
#define Ec  1024
#define Hc  16
#define HDc 64
#define TTc (Bc*Sc)
#define TILE_R 128
#define NTILES 36
#define EPSc 1e-5f
#define LOG2E 1.44269504f
#define C2    (0.125f*LOG2E)

typedef unsigned short u16;
using bf8   = __attribute__((ext_vector_type(8))) short;
using f32x4 = __attribute__((ext_vector_type(4))) float;
#define MFMA(a,b,c) __builtin_amdgcn_mfma_f32_16x16x32_bf16(a,b,c,0,0,0)

static __device__ __forceinline__ u16 f2b(float f){
    return (u16)((__float_as_uint(f) + 0x8000u) >> 16);
}
static __device__ __forceinline__ float b2f(u16 s){
    return __uint_as_float(((unsigned)s) << 16);
}
// raw v_exp_f32 (2^x): inputs here are <= ~8; underflow flushes to 0 which is
// exactly the wanted semantics. Avoids OCML's multi-instruction wrapper.
static __device__ __forceinline__ float ex2(float x){
    return __builtin_amdgcn_exp2f(x);
}
// pack two f32 -> one dword of 2 bf16 (low = a, high = b), single VALU op
static __device__ __forceinline__ unsigned cvtpk(float a, float b){
    unsigned r;
    asm("v_cvt_pk_bf16_f32 %0, %1, %2" : "=v"(r) : "v"(a), "v"(b));
    return r;
}
union bfpack { unsigned u[4]; bf8 v; };
// 3-input max; clang fuses to v_max3_f32
static __device__ __forceinline__ float max3f(float a, float b, float c){
    return fmaxf(fmaxf(a, b), c);
}
// XOR-swizzled LDS addressing: tiles are [R][64] u16, 8-u16 (16B) groups,
// group index col8 swizzled by row&7 -> fragment ds_read_b128 is
// bank-conflict-free.
static __device__ __forceinline__ u16* swz(u16* base, int row, int col8){
    return base + row*64 + ((col8 ^ (row & 7)) << 3);
}
static __device__ __forceinline__ const u16* swzc(const u16* base, int row, int col8){
    return base + row*64 + ((col8 ^ (row & 7)) << 3);
}
// async global->LDS, 16B per lane. LDS dest = wave-uniform base + lane*16
// (linear); the swizzle is applied by inverse-permuting the per-lane global
// source address (rule: linear dest + inv-swz source + swz read).
typedef const __attribute__((address_space(1))) void* gp1;
typedef __attribute__((address_space(3))) void* lp3;
static __device__ __forceinline__ void gl16(const void* g, void* l){
    __builtin_amdgcn_global_load_lds((gp1)g, (lp3)l, 16, 0, 0);
}
// inverse of the k_flash pi row permutation (pi: pr4=g2, pr3=g4, pr2=g3)
static __device__ __forceinline__ int pinv(int lr){
    return (lr & 0x23) | ((lr & 0x10) >> 2) | ((lr & 0x0C) << 1);
}

// ---------------------------------------------------------------------------
// 1. modality-sorted token permutation, 128-padded segments per (b,m).
//    Also zeroes the 4KB zbuf used by gload_lds staging for padding rows.
// ---------------------------------------------------------------------------
__global__ void k_perm(const int* __restrict__ mod, int* __restrict__ perm,
                       int* __restrict__ tmeta, u16* __restrict__ zbuf)
{
    __shared__ int cnt[4], segstart[4];
    int t = threadIdx.x;
    for (int i = t; i < 2048; i += 256) zbuf[i] = 0;
    if (t < 4) cnt[t] = 0;
    __syncthreads();
    for (int i = t; i < TTc; i += 256){
        int b = i >> 11; int m = mod[i];
        atomicAdd(&cnt[b*2+m], 1);
    }
    __syncthreads();
    if (t == 0){
        int off = 0;
        for (int i = 0; i < 4; i++){
            segstart[i] = off;
            int pad = ((cnt[i] + TILE_R - 1)/TILE_R)*TILE_R;
            for (int tt = off/TILE_R; tt < (off+pad)/TILE_R; tt++) tmeta[tt] = i;
            off += pad;
        }
        for (int tt = off/TILE_R; tt < NTILES; tt++) tmeta[tt] = -1;
    }
    __syncthreads();
    if (t < 4) cnt[t] = 0;
    for (int i = t; i < NTILES*TILE_R; i += 256) perm[i] = -1;
    __syncthreads();
    for (int i = t; i < TTc; i += 256){
        int b = i >> 11, s = i & 2047; int m = mod[i];
        int r = atomicAdd(&cnt[b*2+m], 1);
        perm[segstart[b*2+m] + r] = s;
    }
}

// ---------------------------------------------------------------------------
// 2. fused fp32->bf16 conversion: x (plain) + mask (scaled by LOG2E).
//    grid 8192: blocks [0,4096) -> x, [4096,8192) -> mask.
// ---------------------------------------------------------------------------
__global__ __launch_bounds__(256) void k_prep(
    const float* __restrict__ x, const float* __restrict__ mask,
    u16* __restrict__ xb, u16* __restrict__ maskb)
{
    int bid = blockIdx.x;
    if (bid < 4096){
        int i = (bid*256 + threadIdx.x)*4;
        float4 v = *(const float4*)&x[i];
        ushort4 o;
        o.x = f2b(v.x); o.y = f2b(v.y); o.z = f2b(v.z); o.w = f2b(v.w);
        *(ushort4*)&xb[i] = o;
    } else {
        int i = ((bid-4096)*256 + threadIdx.x)*4;
        float4 v = *(const float4*)&mask[i];
        ushort4 o;
        o.x = f2b(v.x*LOG2E); o.y = f2b(v.y*LOG2E);
        o.z = f2b(v.z*LOG2E); o.w = f2b(v.w*LOG2E);
        *(ushort4*)&maskb[i] = o;
    }
}

// ---------------------------------------------------------------------------
// 3. transpose+convert all four weights in one launch; grid (32,32,8)
// ---------------------------------------------------------------------------
__global__ __launch_bounds__(256) void k_tcvt(
    const float* __restrict__ s0, const float* __restrict__ s1,
    const float* __restrict__ s2, const float* __restrict__ s3,
    u16* __restrict__ d0, u16* __restrict__ d1,
    u16* __restrict__ d2, u16* __restrict__ d3)
{
    int wsel = blockIdx.z >> 1, m = blockIdx.z & 1;
    const float* src = (wsel==0?s0:wsel==1?s1:wsel==2?s2:s3) + (size_t)m*1048576;
    u16*       dst = (wsel==0?d0:wsel==1?d1:wsel==2?d2:d3) + (size_t)m*1048576;
    __shared__ float sh[32][33];
    int t = threadIdx.x;
    int i0 = blockIdx.x*32, j0 = blockIdx.y*32;
    {
        int i = t >> 3, j4 = (t & 7)*4;
        *(float4*)&sh[i][j4] = *(const float4*)&src[(size_t)(i0+i)*1024 + j0 + j4];
    }
    __syncthreads();
    {
        int j = t >> 3, i4 = (t & 7)*4;
        ushort4 o;
        o.x = f2b(sh[i4+0][j]); o.y = f2b(sh[i4+1][j]);
        o.z = f2b(sh[i4+2][j]); o.w = f2b(sh[i4+3][j]);
        *(ushort4*)&dst[(size_t)(j0+j)*1024 + i0 + i4] = o;
    }
}

// ---------------------------------------------------------------------------
// 4. QKV projection, MFMA, fused per-head RMSNorm for Q and K.
//    grid (8, NTILES, 3). LDS tiles XOR-swizzled [128][64], staged via
//    global_load_lds (linear dest, inverse-swizzled per-lane source).
//    Q folded with C2 = 0.125*log2e.
// ---------------------------------------------------------------------------
__global__ __launch_bounds__(256) void k_qkv(
    const u16* __restrict__ xb, const u16* __restrict__ wqT,
    const u16* __restrict__ wkT, const u16* __restrict__ wvT,
    const int* __restrict__ perm, const int* __restrict__ tmeta,
    const float* __restrict__ qnw, const float* __restrict__ knw,
    const u16* __restrict__ zbuf,
    u16* __restrict__ qb, u16* __restrict__ kb, u16* __restrict__ vb)
{
    int meta = tmeta[blockIdx.y];
    if (meta < 0) return;
    int b = meta >> 1, m = meta & 1;
    const u16* W = (blockIdx.z==0 ? wqT : (blockIdx.z==1 ? wkT : wvT)) + (size_t)m*Ec*Dc;
    u16* outp    = (blockIdx.z==0 ? qb  : (blockIdx.z==1 ? kb  : vb));
    int c0 = blockIdx.x*128;
    int t = threadIdx.x, lane = t & 63, wv_ = t >> 6;
    int quad = lane >> 4, lc = lane & 15;

    __shared__ u16 at[128*64];
    __shared__ u16 bt[128*64];
    __shared__ int sperm[128];
    if (t < 128) sperm[t] = perm[blockIdx.y*128 + t];
    f32x4 acc[2][8];
    #pragma unroll
    for (int i=0;i<2;i++)
        #pragma unroll
        for (int j=0;j<8;j++) acc[i][j] = (f32x4){0.f,0.f,0.f,0.f};
    __syncthreads();

    // staging sources: wave w instr i lane l covers LDS row w*32+i*8+(l>>3),
    // stored group l&7 -> true col8 = (l&7)^(l>>3) (row&7 == l>>3).
    int colsw = ((lane & 7) ^ (lane >> 3)) << 3;
    const u16* ab[4]; const u16* bb[4];
    #pragma unroll
    for (int i = 0; i < 4; i++){
        int row = wv_*32 + i*8 + (lane >> 3);
        int s_ = sperm[row];
        ab[i] = (s_ >= 0) ? (xb + ((size_t)(b*Sc + s_))*Dc + colsw) : zbuf;
        bb[i] = W + (size_t)(c0 + row)*Dc + colsw;
    }

    for (int d0 = 0; d0 < Dc; d0 += 64){
        #pragma unroll
        for (int i = 0; i < 4; i++){
            gl16(ab[i] + d0, &at[(wv_*4 + i)*512]);
            gl16(bb[i] + d0, &bt[(wv_*4 + i)*512]);
        }
        __syncthreads();
        #pragma unroll
        for (int ks = 0; ks < 2; ks++){
            bf8 a0 = *(const bf8*)swzc(at, wv_*32 + lc,      ks*4 + quad);
            bf8 a1 = *(const bf8*)swzc(at, wv_*32 + 16 + lc, ks*4 + quad);
            #pragma unroll
            for (int nb = 0; nb < 8; nb++){
                bf8 bb2 = *(const bf8*)swzc(bt, nb*16 + lc, ks*4 + quad);
                acc[0][nb] = MFMA(a0, bb2, acc[0][nb]);
                acc[1][nb] = MFMA(a1, bb2, acc[1][nb]);
            }
        }
        __syncthreads();
    }

    if (blockIdx.z < 2){
        const float* nw = (blockIdx.z==0 ? qnw : knw) + m*HDc;
        float cs = (blockIdx.z==0) ? C2 : 1.f;   // fold score scale into Q
        float w0 = nw[lc]*cs, w1 = nw[16+lc]*cs, w2 = nw[32+lc]*cs, w3 = nw[48+lc]*cs;
        #pragma unroll
        for (int mb = 0; mb < 2; mb++){
            #pragma unroll
            for (int r = 0; r < 4; r++){
                #pragma unroll
                for (int g = 0; g < 2; g++){
                    float ss = 0.f;
                    #pragma unroll
                    for (int j = 0; j < 4; j++){
                        float v2 = acc[mb][g*4+j][r];
                        ss += v2*v2;
                    }
                    ss += __shfl_xor(ss, 1, 64);
                    ss += __shfl_xor(ss, 2, 64);
                    ss += __shfl_xor(ss, 4, 64);
                    ss += __shfl_xor(ss, 8, 64);
                    float rs = rsqrtf(ss*(1.f/64.f) + EPSc);
                    acc[mb][g*4+0][r] *= rs*w0;
                    acc[mb][g*4+1][r] *= rs*w1;
                    acc[mb][g*4+2][r] *= rs*w2;
                    acc[mb][g*4+3][r] *= rs*w3;
                }
            }
        }
    }

    int h0 = c0 >> 6;
    #pragma unroll
    for (int mb = 0; mb < 2; mb++){
        #pragma unroll
        for (int r = 0; r < 4; r++){
            int row = wv_*32 + mb*16 + quad*4 + r;
            int s_ = sperm[row];
            if (s_ < 0) continue;
            #pragma unroll
            for (int nb = 0; nb < 8; nb++){
                int col = nb*16 + lc;
                int h = h0 + (col >> 6), hd = col & 63;
                outp[(((size_t)(b*Hc + h))*Sc + s_)*HDc + hd] = f2b(acc[mb][nb][r]);
            }
        }
    }
}

// ---------------------------------------------------------------------------
// 6. V transpose via LDS tiles: vb [BH][S][HD] -> vtb [BH][HD][S]
// ---------------------------------------------------------------------------
__global__ __launch_bounds__(256) void k_vt(const u16* __restrict__ vb,
                                            u16* __restrict__ vtb)
{
    __shared__ u16 sh[64][72];
    int t = threadIdx.x;
    int s0 = blockIdx.x*64, bh = blockIdx.y;
    {
        int rr = t >> 2, cc = (t & 3)*16;
        const u16* src = vb + ((size_t)bh*Sc + s0 + rr)*HDc + cc;
        *(uint4*)&sh[rr][cc]   = *(const uint4*)(src);
        *(uint4*)&sh[rr][cc+8] = *(const uint4*)(src+8);
    }
    __syncthreads();
    {
        int hd = t >> 2, sc = (t & 3)*16;
        u16 tmp[16];
        #pragma unroll
        for (int j = 0; j < 16; j++) tmp[j] = sh[sc+j][hd];
        u16* dst = vtb + ((size_t)bh*HDc + hd)*Sc + s0 + sc;
        *(uint4*)(dst)   = *(const uint4*)&tmp[0];
        *(uint4*)(dst+8) = *(const uint4*)&tmp[8];
    }
}

// ---------------------------------------------------------------------------
// 9. flash PV with ONLINE softmax + defer-max (THR=8), FULL K per block:
//    grid (32, 16, 2): z = b. 1024 blocks = 4 blocks/CU resident.
//    Mask is PRELOADED as the QK^T MFMA C-operand (C slot (row=k, col=q=lc)
//    matches the per-lane mask slots exactly) -> the 16 VALU mask-adds per
//    tile move to the matrix pipe for free.
//    2-phase double-buffered staging (gl16 K/V + mask regs, 1 barrier/tile).
//    Row-sum l via MFMA ones-operand (racc rows == oacc rows); lstc written
//    directly (no split-K).
// ---------------------------------------------------------------------------
__global__ __launch_bounds__(256) void k_flash(
    const u16* __restrict__ qb, const u16* __restrict__ kb,
    const u16* __restrict__ vtb, const u16* __restrict__ maskb,
    float* __restrict__ lstc, u16* __restrict__ c0)
{
    int qs0 = blockIdx.x*64, h = blockIdx.y;
    int b = blockIdx.z;
    int t = threadIdx.x, lane = t & 63, wv_ = t >> 6;
    int quad = lane >> 4, lc = lane & 15;
    __shared__ u16 kt[2][64*64];
    __shared__ u16 vt[2][64*64];
    const u16* qp  = qb  + ((size_t)(b*Hc+h))*Sc*HDc;
    const u16* kp  = kb  + ((size_t)(b*Hc+h))*Sc*HDc;
    const u16* vtp = vtb + ((size_t)(b*Hc+h))*HDc*Sc;
    const u16* mq  = maskb + (size_t)(qs0 + wv_*16 + lc)*Sc;  // this lane's q-row
    bf8 aq[2];
    #pragma unroll
    for (int ks = 0; ks < 2; ks++)
        aq[ks] = *(const bf8*)(qp + (size_t)(qs0 + wv_*16 + lc)*HDc + ks*32 + quad*8);
    // all-ones B fragment for MFMA row sums
    bfpack onep; onep.u[0] = onep.u[1] = onep.u[2] = onep.u[3] = 0x3F803F80u;
    bf8 ones = onep.v;
    // online stats: rm per-lane for q-row lc (quad-replicated); l via racc
    float rm = -1.0e30f;
    f32x4 racc = (f32x4){0.f,0.f,0.f,0.f};
    f32x4 oacc[4];
    #pragma unroll
    for (int j=0;j<4;j++) oacc[j] = (f32x4){0.f,0.f,0.f,0.f};

    // gl16 staging geometry (per wave: rows w*16..w*16+15 of each tile)
    int lsub = lane >> 3;
    int colsw = ((lane & 7) ^ lsub) << 3;
    int lrA = wv_*16 + lsub, lrB = wv_*16 + 8 + lsub;
    const u16* kg0 = kp + (size_t)pinv(lrA)*HDc + colsw;
    const u16* kg1 = kp + (size_t)pinv(lrB)*HDc + colsw;
    const u16* vg0 = vtp + (size_t)lrA*Sc + colsw;
    const u16* vg1 = vtp + (size_t)lrB*Sc + colsw;
    int kdo0 = (wv_*16 + 0)*64, kdo1 = (wv_*16 + 8)*64;

    // prologue: stage tile 0 into buffer 0, prefetch its mask
    gl16(kg0, &kt[0][kdo0]);
    gl16(kg1, &kt[0][kdo1]);
    gl16(vg0, &vt[0][kdo0]);
    gl16(vg1, &vt[0][kdo1]);
    ushort4 mv[2][2];
    #pragma unroll
    for (int a1 = 0; a1 < 2; a1++)
        #pragma unroll
        for (int b1 = 0; b1 < 2; b1++)
            mv[a1][b1] = *(const ushort4*)(mq + a1*32 + quad*8 + b1*4);
    __syncthreads();   // drains prologue staging -> buffer 0 ready

    int cur = 0;
    for (int kc = 0; kc < Sc; kc += 64){
        // stage NEXT tile into the shadow buffer (clamped on last iter;
        // redundant loads land in the unused buffer, drained by last barrier)
        int nxt = (kc + 64 < Sc) ? kc + 64 : kc;
        gl16(kg0 + (size_t)nxt*HDc, &kt[cur^1][kdo0]);
        gl16(kg1 + (size_t)nxt*HDc, &kt[cur^1][kdo1]);
        gl16(vg0 + nxt, &vt[cur^1][kdo0]);
        gl16(vg1 + nxt, &vt[cur^1][kdo1]);
        ushort4 mvn[2][2];
        #pragma unroll
        for (int a1 = 0; a1 < 2; a1++)
            #pragma unroll
            for (int b1 = 0; b1 < 2; b1++)
                mvn[a1][b1] = *(const ushort4*)(mq + nxt + a1*32 + quad*8 + b1*4);

        const u16* ktc = kt[cur];
        const u16* vtc = vt[cur];
        // S^T = K * Q^T with the mask preloaded as the C operand
        f32x4 acc[4];
        #pragma unroll
        for (int a1 = 0; a1 < 2; a1++){
            #pragma unroll
            for (int b1 = 0; b1 < 2; b1++){
                int nb = 2*a1 + b1;
                acc[nb][0] = b2f(mv[a1][b1].x);
                acc[nb][1] = b2f(mv[a1][b1].y);
                acc[nb][2] = b2f(mv[a1][b1].z);
                acc[nb][3] = b2f(mv[a1][b1].w);
            }
        }
        #pragma unroll
        for (int ks = 0; ks < 2; ks++){
            #pragma unroll
            for (int nb = 0; nb < 4; nb++){
                bf8 ak = *(const bf8*)swzc(ktc, nb*16 + lc, ks*4 + quad);
                acc[nb] = MFMA(ak, aq[ks], acc[nb]);
            }
        }
        // per-lane max via max3 tree (acc already includes mask)
        float m0_ = max3f(acc[0][0], acc[0][1], acc[0][2]);
        float m1_ = max3f(acc[0][3], acc[1][0], acc[1][1]);
        float m2_ = max3f(acc[1][2], acc[1][3], acc[2][0]);
        float m3_ = max3f(acc[2][1], acc[2][2], acc[2][3]);
        float m4_ = max3f(acc[3][0], acc[3][1], acc[3][2]);
        float mxl = fmaxf(max3f(m0_, m1_, m2_), max3f(m3_, m4_, acc[3][3]));
        // defer-max: only reduce/rescale when some lane grew past rm + 8
        if (__any(mxl > rm + 8.f)){
            float mx = fmaxf(mxl, __shfl_xor(mxl, 16, 64));
            mx = fmaxf(mx, __shfl_xor(mx, 32, 64));
            float nm = fmaxf(rm, mx);
            float fac = ex2(rm - nm);
            rm = nm;
            float f0 = __shfl(fac, quad*4+0, 64);
            float f1 = __shfl(fac, quad*4+1, 64);
            float f2 = __shfl(fac, quad*4+2, 64);
            float f3 = __shfl(fac, quad*4+3, 64);
            racc[0] *= f0; racc[1] *= f1; racc[2] *= f2; racc[3] *= f3;
            #pragma unroll
            for (int nb = 0; nb < 4; nb++){
                oacc[nb][0] *= f0; oacc[nb][1] *= f1;
                oacc[nb][2] *= f2; oacc[nb][3] *= f3;
            }
        }
        // P (bounded by 2^8) packed via cvt_pk straight into PV A-fragments;
        // row sums accumulated on the matrix pipe via the ones fragment.
        #pragma unroll
        for (int a1 = 0; a1 < 2; a1++){
            bfpack pk;
            pk.u[0] = cvtpk(ex2(acc[2*a1][0] - rm),   ex2(acc[2*a1][1] - rm));
            pk.u[1] = cvtpk(ex2(acc[2*a1][2] - rm),   ex2(acc[2*a1][3] - rm));
            pk.u[2] = cvtpk(ex2(acc[2*a1+1][0] - rm), ex2(acc[2*a1+1][1] - rm));
            pk.u[3] = cvtpk(ex2(acc[2*a1+1][2] - rm), ex2(acc[2*a1+1][3] - rm));
            bf8 ap = pk.v;
            racc = MFMA(ap, ones, racc);
            #pragma unroll
            for (int nb2 = 0; nb2 < 4; nb2++){
                bf8 bv = *(const bf8*)swzc(vtc, nb2*16 + lc, a1*4 + quad);
                oacc[nb2] = MFMA(ap, bv, oacc[nb2]);
            }
        }
        __syncthreads();   // one barrier/tile: drains shadow staging + ds_reads
        #pragma unroll
        for (int a1 = 0; a1 < 2; a1++)
            #pragma unroll
            for (int b1 = 0; b1 < 2; b1++)
                mv[a1][b1] = mvn[a1][b1];
        cur ^= 1;
    }
    // lstc = rm + log2(l): rm is quad-replicated per lc, so shfl from lanes
    // 0..15 (always valid) pairs row quad*4+r's rm with racc[r] on lc==0.
    float rmr[4];
    #pragma unroll
    for (int r = 0; r < 4; r++) rmr[r] = __shfl(rm, quad*4 + r, 64);
    size_t sbase = ((size_t)(b*Hc+h))*Sc + qs0 + wv_*16;
    if (lc == 0){
        #pragma unroll
        for (int r = 0; r < 4; r++)
            lstc[sbase + quad*4 + r] = rmr[r] + log2f(racc[r]);
    }
    // ctx normalized by the full row-sum (racc rows match oacc rows)
    #pragma unroll
    for (int r = 0; r < 4; r++){
        float ir = 1.f/racc[r];
        int tok = qs0 + wv_*16 + quad*4 + r;
        #pragma unroll
        for (int nb = 0; nb < 4; nb++){
            int hd = nb*16 + lc;
            c0[((size_t)(b*Sc + tok))*Ec + h*HDc + hd] = f2b(oacc[nb][r]*ir);
        }
    }
}

// ---------------------------------------------------------------------------
// 8. attn_weights: q-tile 64, k-tile 64, loop all 16 h, NO atomics.
//    grid (32, 32, 2) = (q, k, b). -lstc preloaded as the MFMA C-operand
//    (negation folded into the scc staging store) -> exp2 input is acc
//    directly, 16 VALU subs per h-iter deleted. Q pre-scaled by C2.
// ---------------------------------------------------------------------------
__global__ __launch_bounds__(256) void k_attnw(
    const u16* __restrict__ qb, const u16* __restrict__ kb,
    const u16* __restrict__ maskb, const float* __restrict__ lstc,
    float* __restrict__ awout)
{
    int qs0 = blockIdx.x*64, ks0 = blockIdx.y*64, b = blockIdx.z;
    int t = threadIdx.x, lane = t & 63, wv_ = t >> 6;
    int quad = lane >> 4, lc = lane & 15;
    __shared__ u16 kt[64*64];
    __shared__ float scc[64];
    f32x4 T[4];
    #pragma unroll
    for (int j=0;j<4;j++) T[j] = (f32x4){0.f,0.f,0.f,0.f};

    int lsub = lane >> 3;
    int colsw = ((lane & 7) ^ lsub) << 3;
    int lrA = wv_*16 + lsub, lrB = wv_*16 + 8 + lsub;
    u16* kd0 = &kt[(wv_*16 + 0)*64];
    u16* kd1 = &kt[(wv_*16 + 8)*64];

    for (int h = 0; h < Hc; h++){
        __syncthreads();
        const u16* qp = qb + ((size_t)(b*Hc+h))*Sc*HDc;
        const u16* kp = kb + ((size_t)(b*Hc+h))*Sc*HDc;
        bf8 aq[2];
        #pragma unroll
        for (int ks = 0; ks < 2; ks++)
            aq[ks] = *(const bf8*)(qp + (size_t)(qs0 + wv_*16 + lc)*HDc + ks*32 + quad*8);
        gl16(kp + (size_t)(ks0 + lrA)*HDc + colsw, kd0);
        gl16(kp + (size_t)(ks0 + lrB)*HDc + colsw, kd1);
        if (t < 64)
            scc[t] = -lstc[((size_t)(b*Hc+h))*Sc + qs0 + t];   // negated
        __syncthreads();
        // C init = -lstc for this lane's 4 output rows (consecutive floats)
        f32x4 minit = *(const f32x4*)&scc[wv_*16 + quad*4];
        f32x4 acc[4];
        #pragma unroll
        for (int j=0;j<4;j++) acc[j] = minit;
        #pragma unroll
        for (int ks = 0; ks < 2; ks++){
            #pragma unroll
            for (int nb = 0; nb < 4; nb++){
                bf8 bb = *(const bf8*)swzc(kt, nb*16 + lc, ks*4 + quad);
                acc[nb] = MFMA(aq[ks], bb, acc[nb]);
            }
        }
        #pragma unroll
        for (int r = 0; r < 4; r++){
            #pragma unroll
            for (int nb = 0; nb < 4; nb++)
                T[nb][r] += ex2(acc[nb][r]);
        }
    }
    #pragma unroll
    for (int r = 0; r < 4; r++){
        int gq = qs0 + wv_*16 + quad*4 + r;
        #pragma unroll
        for (int nb = 0; nb < 4; nb++){
            int gk = ks0 + nb*16 + lc;
            float mk = b2f(maskb[(size_t)gq*Sc + gk]);   // mask*log2e
            awout[(size_t)b*Sc*Sc + (size_t)gq*Sc + gk]
                = T[nb][r]*ex2(mk)*(1.f/16.f);
        }
    }
}

// ---------------------------------------------------------------------------
// 10. output projection, MFMA. grid (8, NTILES). XOR-swizzled tiles staged
//     via global_load_lds (same mapping as k_qkv).
// ---------------------------------------------------------------------------
__global__ __launch_bounds__(256) void k_oproj(
    const u16* __restrict__ ctxb, const u16* __restrict__ woT,
    const int* __restrict__ perm, const int* __restrict__ tmeta,
    const u16* __restrict__ zbuf, float* __restrict__ opre)
{
    int meta = tmeta[blockIdx.y];
    if (meta < 0) return;
    int b = meta >> 1, m = meta & 1;
    const u16* W = woT + (size_t)m*Ec*Dc;
    int c0 = blockIdx.x*128;
    int t = threadIdx.x, lane = t & 63, wv_ = t >> 6;
    int quad = lane >> 4, lc = lane & 15;
    __shared__ u16 at[128*64];
    __shared__ u16 bt[128*64];
    __shared__ int sperm[128];
    if (t < 128) sperm[t] = perm[blockIdx.y*128 + t];
    f32x4 acc[2][8];
    #pragma unroll
    for (int i=0;i<2;i++)
        #pragma unroll
        for (int j=0;j<8;j++) acc[i][j] = (f32x4){0.f,0.f,0.f,0.f};
    __syncthreads();

    int colsw = ((lane & 7) ^ (lane >> 3)) << 3;
    const u16* ab[4]; const u16* bb[4];
    #pragma unroll
    for (int i = 0; i < 4; i++){
        int row = wv_*32 + i*8 + (lane >> 3);
        int s_ = sperm[row];
        ab[i] = (s_ >= 0) ? (ctxb + ((size_t)(b*Sc + s_))*Ec + colsw) : zbuf;
        bb[i] = W + (size_t)(c0 + row)*Ec + colsw;
    }

    for (int d0 = 0; d0 < Ec; d0 += 64){
        #pragma unroll
        for (int i = 0; i < 4; i++){
            gl16(ab[i] + d0, &at[(wv_*4 + i)*512]);
            gl16(bb[i] + d0, &bt[(wv_*4 + i)*512]);
        }
        __syncthreads();
        #pragma unroll
        for (int ks = 0; ks < 2; ks++){
            bf8 a0 = *(const bf8*)swzc(at, wv_*32 + lc,      ks*4 + quad);
            bf8 a1 = *(const bf8*)swzc(at, wv_*32 + 16 + lc, ks*4 + quad);
            #pragma unroll
            for (int nb = 0; nb < 8; nb++){
                bf8 bb2 = *(const bf8*)swzc(bt, nb*16 + lc, ks*4 + quad);
                acc[0][nb] = MFMA(a0, bb2, acc[0][nb]);
                acc[1][nb] = MFMA(a1, bb2, acc[1][nb]);
            }
        }
        __syncthreads();
    }
    #pragma unroll
    for (int mb = 0; mb < 2; mb++){
        #pragma unroll
        for (int r = 0; r < 4; r++){
            int row = wv_*32 + mb*16 + quad*4 + r;
            int s_ = sperm[row];
            if (s_ < 0) continue;
            #pragma unroll
            for (int nb = 0; nb < 8; nb++){
                int col = c0 + nb*16 + lc;
                opre[((size_t)(b*Sc + s_))*Dc + col] = acc[mb][nb][r];
            }
        }
    }
}

// ---------------------------------------------------------------------------
// 11. final RMSNorm over D -> out
// ---------------------------------------------------------------------------
__global__ __launch_bounds__(256) void k_onorm(
    const float* __restrict__ opre, const float* __restrict__ anw,
    const int* __restrict__ mod, float* __restrict__ out)
{
    int row = blockIdx.x;
    int m = mod[row];
    int t = threadIdx.x;
    float val[4];
    float ss = 0.f;
    #pragma unroll
    for (int j=0;j<4;j++){
        val[j] = opre[(size_t)row*Dc + t + 256*j];
        ss += val[j]*val[j];
    }
    #pragma unroll
    for (int o=32;o>0;o>>=1) ss += __shfl_xor(ss, o, 64);
    __shared__ float red[4];
    int wid = t>>6, lane = t&63;
    if (lane==0) red[wid]=ss;
    __syncthreads();
    float tot = red[0]+red[1]+red[2]+red[3];
    float rms = rsqrtf(tot*(1.f/1024.f) + EPSc);
    #pragma unroll
    for (int j=0;j<4;j++)
        out[(size_t)row*Dc + t + 256*j] = val[j]*rms*anw[m*Dc + t + 256*j];
}

// ---------------------------------------------------------------------------
extern "C" void kernel_launch(void* const* d_in, const int* in_sizes, int n_in,
                              void* d_out, int out_size, void* d_ws, size_t ws_size,
                              hipStream_t stream)
{
    const float* x    = (const float*)d_in[0];
    const float* mask = (const float*)d_in[1];
    const int*   mod  = (const int*)  d_in[2];
    const float* Wq   = (const float*)d_in[3];
    const float* Wk   = (const float*)d_in[4];
    const float* Wv   = (const float*)d_in[5];
    const float* Wo   = (const float*)d_in[6];
    const float* qnw  = (const float*)d_in[7];
    const float* knw  = (const float*)d_in[8];
    const float* anw  = (const float*)d_in[9];

    float* out   = (float*)d_out;                 // [B,S,D]
    float* awout = out + (size_t)Bc*Sc*Dc;        // [B,S,S]

    float* ws = (float*)d_ws;
    u16* qb    = (u16*)(ws + 0);
    u16* kb    = (u16*)(ws + 2097152);
    u16* vb    = (u16*)(ws + 4194304);   // dead after k_vt
    u16* xb    = (u16*)(ws + 6291456);   // dead after k_qkv -> ctx
    u16* ctx0  = xb;
    u16* vtb   = (u16*)(ws + 8388608);
    u16* wqT   = (u16*)(ws + 10485760);
    u16* wkT   = (u16*)(ws + 11534336);
    u16* wvT   = (u16*)(ws + 12582912);
    u16* woT   = (u16*)(ws + 13631488);
    float* lstc= ws + 14680064;          // rm + log2(l), 65536
    u16* maskb = (u16*)(ws + 15335424);  // mask*log2e, bf16
    int* perm  = (int*)(ws + 17432576);
    int* tmeta = perm + NTILES*TILE_R;
    u16* zbuf  = (u16*)(tmeta + NTILES + 28);   // 4KB zero scratch (aligned)
    float* opre = ws;                    // aliases qb+kb (dead by then)

    k_perm  <<<dim3(1),            256, 0, stream>>>(mod, perm, tmeta, zbuf);
    k_prep  <<<dim3(8192),         256, 0, stream>>>(x, mask, xb, maskb);
    k_tcvt  <<<dim3(32,32,8),      256, 0, stream>>>(Wq, Wk, Wv, Wo, wqT, wkT, wvT, woT);
    k_qkv   <<<dim3(8,NTILES,3),   256, 0, stream>>>(xb, wqT, wkT, wvT, perm, tmeta,
                                                     qnw, knw, zbuf, qb, kb, vb);
    k_vt    <<<dim3(32,32),        256, 0, stream>>>(vb, vtb);
    k_flash <<<dim3(32,16,2),      256, 0, stream>>>(qb, kb, vtb, maskb, lstc, ctx0);
    k_attnw <<<dim3(32,32,2),      256, 0, stream>>>(qb, kb, maskb, lstc, awout);
    k_oproj <<<dim3(8,NTILES),     256, 0, stream>>>(ctx0, woT, perm, tmeta, zbuf, opre);
    k_onorm <<<dim3(4096),         256, 0, stream>>>(opre, anw, mod, out);
}

// Round 13
// 321.893 us; speedup vs baseline: 1.2032x; 1.0486x over previous
//
#include <hip/hip_runtime.h>
#include <cstdint>

#define Bc  2
#define Sc  2048
#define Dc  1024
#define Ec  1024
#define Hc  16
#define HDc 64
#define TTc (Bc*Sc)
#define TILE_R 128
#define NTILES 36
#define EPSc 1e-5f
#define LOG2E 1.44269504f
#define C2    (0.125f*LOG2E)

typedef unsigned short u16;
using bf8   = __attribute__((ext_vector_type(8))) short;
using f32x4 = __attribute__((ext_vector_type(4))) float;
#define MFMA(a,b,c) __builtin_amdgcn_mfma_f32_16x16x32_bf16(a,b,c,0,0,0)

static __device__ __forceinline__ u16 f2b(float f){
    return (u16)((__float_as_uint(f) + 0x8000u) >> 16);
}
static __device__ __forceinline__ float b2f(u16 s){
    return __uint_as_float(((unsigned)s) << 16);
}
// raw v_exp_f32 (2^x): inputs here are <= ~8; underflow flushes to 0 which is
// exactly the wanted semantics. Avoids OCML's multi-instruction wrapper.
static __device__ __forceinline__ float ex2(float x){
    return __builtin_amdgcn_exp2f(x);
}
// pack two f32 -> one dword of 2 bf16 (low = a, high = b), single VALU op
static __device__ __forceinline__ unsigned cvtpk(float a, float b){
    unsigned r;
    asm("v_cvt_pk_bf16_f32 %0, %1, %2" : "=v"(r) : "v"(a), "v"(b));
    return r;
}
union bfpack { unsigned u[4]; bf8 v; };
// 3-input max; clang fuses to v_max3_f32
static __device__ __forceinline__ float max3f(float a, float b, float c){
    return fmaxf(fmaxf(a, b), c);
}
// XOR-swizzled LDS addressing: tiles are [R][64] u16, 8-u16 (16B) groups,
// group index col8 swizzled by row&7 -> fragment ds_read_b128 is
// bank-conflict-free.
static __device__ __forceinline__ u16* swz(u16* base, int row, int col8){
    return base + row*64 + ((col8 ^ (row & 7)) << 3);
}
static __device__ __forceinline__ const u16* swzc(const u16* base, int row, int col8){
    return base + row*64 + ((col8 ^ (row & 7)) << 3);
}
// async global->LDS, 16B per lane. LDS dest = wave-uniform base + lane*16
// (linear); the swizzle is applied by inverse-permuting the per-lane global
// source address (rule: linear dest + inv-swz source + swz read).
typedef const __attribute__((address_space(1))) void* gp1;
typedef __attribute__((address_space(3))) void* lp3;
static __device__ __forceinline__ void gl16(const void* g, void* l){
    __builtin_amdgcn_global_load_lds((gp1)g, (lp3)l, 16, 0, 0);
}
// inverse of the k_flash pi row permutation (pi: pr4=g2, pr3=g4, pr2=g3)
static __device__ __forceinline__ int pinv(int lr){
    return (lr & 0x23) | ((lr & 0x10) >> 2) | ((lr & 0x0C) << 1);
}

// ---------------------------------------------------------------------------
// 1. fused preprocessing, one launch. Block ranges:
//    [0,4096)      x fp32->bf16
//    [4096,8192)   mask fp32->bf16 * LOG2E
//    [8192,16384)  weight transpose+convert (4 weights x 2 modalities)
//    16384         modality-sorted token permutation + zbuf clear
// ---------------------------------------------------------------------------
__global__ __launch_bounds__(256) void k_pre(
    const float* __restrict__ x, const float* __restrict__ mask,
    const int* __restrict__ mod,
    const float* __restrict__ s0, const float* __restrict__ s1,
    const float* __restrict__ s2, const float* __restrict__ s3,
    u16* __restrict__ xb, u16* __restrict__ maskb,
    u16* __restrict__ d0, u16* __restrict__ d1,
    u16* __restrict__ d2, u16* __restrict__ d3,
    int* __restrict__ perm, int* __restrict__ tmeta, u16* __restrict__ zbuf)
{
    int bid = blockIdx.x;
    int t = threadIdx.x;
    if (bid < 4096){
        int i = (bid*256 + t)*4;
        float4 v = *(const float4*)&x[i];
        ushort4 o;
        o.x = f2b(v.x); o.y = f2b(v.y); o.z = f2b(v.z); o.w = f2b(v.w);
        *(ushort4*)&xb[i] = o;
    } else if (bid < 8192){
        int i = ((bid-4096)*256 + t)*4;
        float4 v = *(const float4*)&mask[i];
        ushort4 o;
        o.x = f2b(v.x*LOG2E); o.y = f2b(v.y*LOG2E);
        o.z = f2b(v.z*LOG2E); o.w = f2b(v.w*LOG2E);
        *(ushort4*)&maskb[i] = o;
    } else if (bid < 16384){
        int id = bid - 8192;
        int z = id >> 10, xy = id & 1023;
        int wsel = z >> 1, m = z & 1;
        const float* src = (wsel==0?s0:wsel==1?s1:wsel==2?s2:s3) + (size_t)m*1048576;
        u16*       dst = (wsel==0?d0:wsel==1?d1:wsel==2?d2:d3) + (size_t)m*1048576;
        __shared__ float sh[32][33];
        int i0 = (xy & 31)*32, j0 = (xy >> 5)*32;
        {
            int i = t >> 3, j4 = (t & 7)*4;
            *(float4*)&sh[i][j4] = *(const float4*)&src[(size_t)(i0+i)*1024 + j0 + j4];
        }
        __syncthreads();
        {
            int j = t >> 3, i4 = (t & 7)*4;
            ushort4 o;
            o.x = f2b(sh[i4+0][j]); o.y = f2b(sh[i4+1][j]);
            o.z = f2b(sh[i4+2][j]); o.w = f2b(sh[i4+3][j]);
            *(ushort4*)&dst[(size_t)(j0+j)*1024 + i0 + i4] = o;
        }
    } else {
        __shared__ int cnt[4], segstart[4];
        for (int i = t; i < 2048; i += 256) zbuf[i] = 0;
        if (t < 4) cnt[t] = 0;
        __syncthreads();
        for (int i = t; i < TTc; i += 256){
            int b = i >> 11; int m = mod[i];
            atomicAdd(&cnt[b*2+m], 1);
        }
        __syncthreads();
        if (t == 0){
            int off = 0;
            for (int i = 0; i < 4; i++){
                segstart[i] = off;
                int pad = ((cnt[i] + TILE_R - 1)/TILE_R)*TILE_R;
                for (int tt = off/TILE_R; tt < (off+pad)/TILE_R; tt++) tmeta[tt] = i;
                off += pad;
            }
            for (int tt = off/TILE_R; tt < NTILES; tt++) tmeta[tt] = -1;
        }
        __syncthreads();
        if (t < 4) cnt[t] = 0;
        for (int i = t; i < NTILES*TILE_R; i += 256) perm[i] = -1;
        __syncthreads();
        for (int i = t; i < TTc; i += 256){
            int b = i >> 11, s = i & 2047; int m = mod[i];
            int r = atomicAdd(&cnt[b*2+m], 1);
            perm[segstart[b*2+m] + r] = s;
        }
    }
}

// ---------------------------------------------------------------------------
// 4. QKV projection, MFMA, fused per-head RMSNorm for Q and K.
//    grid (8, NTILES, 3). LDS tiles XOR-swizzled [128][64], staged via
//    global_load_lds (linear dest, inverse-swizzled per-lane source).
//    Q folded with C2 = 0.125*log2e.
// ---------------------------------------------------------------------------
__global__ __launch_bounds__(256) void k_qkv(
    const u16* __restrict__ xb, const u16* __restrict__ wqT,
    const u16* __restrict__ wkT, const u16* __restrict__ wvT,
    const int* __restrict__ perm, const int* __restrict__ tmeta,
    const float* __restrict__ qnw, const float* __restrict__ knw,
    const u16* __restrict__ zbuf,
    u16* __restrict__ qb, u16* __restrict__ kb, u16* __restrict__ vb)
{
    int meta = tmeta[blockIdx.y];
    if (meta < 0) return;
    int b = meta >> 1, m = meta & 1;
    const u16* W = (blockIdx.z==0 ? wqT : (blockIdx.z==1 ? wkT : wvT)) + (size_t)m*Ec*Dc;
    u16* outp    = (blockIdx.z==0 ? qb  : (blockIdx.z==1 ? kb  : vb));
    int c0 = blockIdx.x*128;
    int t = threadIdx.x, lane = t & 63, wv_ = t >> 6;
    int quad = lane >> 4, lc = lane & 15;

    __shared__ u16 at[128*64];
    __shared__ u16 bt[128*64];
    __shared__ int sperm[128];
    if (t < 128) sperm[t] = perm[blockIdx.y*128 + t];
    f32x4 acc[2][8];
    #pragma unroll
    for (int i=0;i<2;i++)
        #pragma unroll
        for (int j=0;j<8;j++) acc[i][j] = (f32x4){0.f,0.f,0.f,0.f};
    __syncthreads();

    int colsw = ((lane & 7) ^ (lane >> 3)) << 3;
    const u16* ab[4]; const u16* bb[4];
    #pragma unroll
    for (int i = 0; i < 4; i++){
        int row = wv_*32 + i*8 + (lane >> 3);
        int s_ = sperm[row];
        ab[i] = (s_ >= 0) ? (xb + ((size_t)(b*Sc + s_))*Dc + colsw) : zbuf;
        bb[i] = W + (size_t)(c0 + row)*Dc + colsw;
    }

    for (int d0 = 0; d0 < Dc; d0 += 64){
        #pragma unroll
        for (int i = 0; i < 4; i++){
            gl16(ab[i] + d0, &at[(wv_*4 + i)*512]);
            gl16(bb[i] + d0, &bt[(wv_*4 + i)*512]);
        }
        __syncthreads();
        #pragma unroll
        for (int ks = 0; ks < 2; ks++){
            bf8 a0 = *(const bf8*)swzc(at, wv_*32 + lc,      ks*4 + quad);
            bf8 a1 = *(const bf8*)swzc(at, wv_*32 + 16 + lc, ks*4 + quad);
            #pragma unroll
            for (int nb = 0; nb < 8; nb++){
                bf8 bb2 = *(const bf8*)swzc(bt, nb*16 + lc, ks*4 + quad);
                acc[0][nb] = MFMA(a0, bb2, acc[0][nb]);
                acc[1][nb] = MFMA(a1, bb2, acc[1][nb]);
            }
        }
        __syncthreads();
    }

    if (blockIdx.z < 2){
        const float* nw = (blockIdx.z==0 ? qnw : knw) + m*HDc;
        float cs = (blockIdx.z==0) ? C2 : 1.f;   // fold score scale into Q
        float w0 = nw[lc]*cs, w1 = nw[16+lc]*cs, w2 = nw[32+lc]*cs, w3 = nw[48+lc]*cs;
        #pragma unroll
        for (int mb = 0; mb < 2; mb++){
            #pragma unroll
            for (int r = 0; r < 4; r++){
                #pragma unroll
                for (int g = 0; g < 2; g++){
                    float ss = 0.f;
                    #pragma unroll
                    for (int j = 0; j < 4; j++){
                        float v2 = acc[mb][g*4+j][r];
                        ss += v2*v2;
                    }
                    ss += __shfl_xor(ss, 1, 64);
                    ss += __shfl_xor(ss, 2, 64);
                    ss += __shfl_xor(ss, 4, 64);
                    ss += __shfl_xor(ss, 8, 64);
                    float rs = rsqrtf(ss*(1.f/64.f) + EPSc);
                    acc[mb][g*4+0][r] *= rs*w0;
                    acc[mb][g*4+1][r] *= rs*w1;
                    acc[mb][g*4+2][r] *= rs*w2;
                    acc[mb][g*4+3][r] *= rs*w3;
                }
            }
        }
    }

    int h0 = c0 >> 6;
    #pragma unroll
    for (int mb = 0; mb < 2; mb++){
        #pragma unroll
        for (int r = 0; r < 4; r++){
            int row = wv_*32 + mb*16 + quad*4 + r;
            int s_ = sperm[row];
            if (s_ < 0) continue;
            #pragma unroll
            for (int nb = 0; nb < 8; nb++){
                int col = nb*16 + lc;
                int h = h0 + (col >> 6), hd = col & 63;
                outp[(((size_t)(b*Hc + h))*Sc + s_)*HDc + hd] = f2b(acc[mb][nb][r]);
            }
        }
    }
}

// ---------------------------------------------------------------------------
// 6. V transpose via LDS tiles: vb [BH][S][HD] -> vtb [BH][HD][S]
// ---------------------------------------------------------------------------
__global__ __launch_bounds__(256) void k_vt(const u16* __restrict__ vb,
                                            u16* __restrict__ vtb)
{
    __shared__ u16 sh[64][72];
    int t = threadIdx.x;
    int s0 = blockIdx.x*64, bh = blockIdx.y;
    {
        int rr = t >> 2, cc = (t & 3)*16;
        const u16* src = vb + ((size_t)bh*Sc + s0 + rr)*HDc + cc;
        *(uint4*)&sh[rr][cc]   = *(const uint4*)(src);
        *(uint4*)&sh[rr][cc+8] = *(const uint4*)(src+8);
    }
    __syncthreads();
    {
        int hd = t >> 2, sc = (t & 3)*16;
        u16 tmp[16];
        #pragma unroll
        for (int j = 0; j < 16; j++) tmp[j] = sh[sc+j][hd];
        u16* dst = vtb + ((size_t)bh*HDc + hd)*Sc + s0 + sc;
        *(uint4*)(dst)   = *(const uint4*)&tmp[0];
        *(uint4*)(dst+8) = *(const uint4*)&tmp[8];
    }
}

// ---------------------------------------------------------------------------
// 9. flash PV with ONLINE softmax + defer-max (THR=8), FULL K per block:
//    grid (32, 16, 2): z = b. Mask preloaded as the QK^T MFMA C-operand.
//    2-phase double-buffered staging (gl16 K/V + mask regs, 1 barrier/tile).
//    Row-sum l via MFMA ones-operand; lstc written directly (no split-K).
// ---------------------------------------------------------------------------
__global__ __launch_bounds__(256) void k_flash(
    const u16* __restrict__ qb, const u16* __restrict__ kb,
    const u16* __restrict__ vtb, const u16* __restrict__ maskb,
    float* __restrict__ lstc, u16* __restrict__ c0)
{
    int qs0 = blockIdx.x*64, h = blockIdx.y;
    int b = blockIdx.z;
    int t = threadIdx.x, lane = t & 63, wv_ = t >> 6;
    int quad = lane >> 4, lc = lane & 15;
    __shared__ u16 kt[2][64*64];
    __shared__ u16 vt[2][64*64];
    const u16* qp  = qb  + ((size_t)(b*Hc+h))*Sc*HDc;
    const u16* kp  = kb  + ((size_t)(b*Hc+h))*Sc*HDc;
    const u16* vtp = vtb + ((size_t)(b*Hc+h))*HDc*Sc;
    const u16* mq  = maskb + (size_t)(qs0 + wv_*16 + lc)*Sc;  // this lane's q-row
    bf8 aq[2];
    #pragma unroll
    for (int ks = 0; ks < 2; ks++)
        aq[ks] = *(const bf8*)(qp + (size_t)(qs0 + wv_*16 + lc)*HDc + ks*32 + quad*8);
    // all-ones B fragment for MFMA row sums
    bfpack onep; onep.u[0] = onep.u[1] = onep.u[2] = onep.u[3] = 0x3F803F80u;
    bf8 ones = onep.v;
    // online stats: rm per-lane for q-row lc (quad-replicated); l via racc
    float rm = -1.0e30f;
    f32x4 racc = (f32x4){0.f,0.f,0.f,0.f};
    f32x4 oacc[4];
    #pragma unroll
    for (int j=0;j<4;j++) oacc[j] = (f32x4){0.f,0.f,0.f,0.f};

    // gl16 staging geometry (per wave: rows w*16..w*16+15 of each tile)
    int lsub = lane >> 3;
    int colsw = ((lane & 7) ^ lsub) << 3;
    int lrA = wv_*16 + lsub, lrB = wv_*16 + 8 + lsub;
    const u16* kg0 = kp + (size_t)pinv(lrA)*HDc + colsw;
    const u16* kg1 = kp + (size_t)pinv(lrB)*HDc + colsw;
    const u16* vg0 = vtp + (size_t)lrA*Sc + colsw;
    const u16* vg1 = vtp + (size_t)lrB*Sc + colsw;
    int kdo0 = (wv_*16 + 0)*64, kdo1 = (wv_*16 + 8)*64;

    // prologue: stage tile 0 into buffer 0, prefetch its mask
    gl16(kg0, &kt[0][kdo0]);
    gl16(kg1, &kt[0][kdo1]);
    gl16(vg0, &vt[0][kdo0]);
    gl16(vg1, &vt[0][kdo1]);
    ushort4 mv[2][2];
    #pragma unroll
    for (int a1 = 0; a1 < 2; a1++)
        #pragma unroll
        for (int b1 = 0; b1 < 2; b1++)
            mv[a1][b1] = *(const ushort4*)(mq + a1*32 + quad*8 + b1*4);
    __syncthreads();   // drains prologue staging -> buffer 0 ready

    int cur = 0;
    for (int kc = 0; kc < Sc; kc += 64){
        int nxt = (kc + 64 < Sc) ? kc + 64 : kc;
        gl16(kg0 + (size_t)nxt*HDc, &kt[cur^1][kdo0]);
        gl16(kg1 + (size_t)nxt*HDc, &kt[cur^1][kdo1]);
        gl16(vg0 + nxt, &vt[cur^1][kdo0]);
        gl16(vg1 + nxt, &vt[cur^1][kdo1]);
        ushort4 mvn[2][2];
        #pragma unroll
        for (int a1 = 0; a1 < 2; a1++)
            #pragma unroll
            for (int b1 = 0; b1 < 2; b1++)
                mvn[a1][b1] = *(const ushort4*)(mq + nxt + a1*32 + quad*8 + b1*4);

        const u16* ktc = kt[cur];
        const u16* vtc = vt[cur];
        // S^T = K * Q^T with the mask preloaded as the C operand
        f32x4 acc[4];
        #pragma unroll
        for (int a1 = 0; a1 < 2; a1++){
            #pragma unroll
            for (int b1 = 0; b1 < 2; b1++){
                int nb = 2*a1 + b1;
                acc[nb][0] = b2f(mv[a1][b1].x);
                acc[nb][1] = b2f(mv[a1][b1].y);
                acc[nb][2] = b2f(mv[a1][b1].z);
                acc[nb][3] = b2f(mv[a1][b1].w);
            }
        }
        #pragma unroll
        for (int ks = 0; ks < 2; ks++){
            #pragma unroll
            for (int nb = 0; nb < 4; nb++){
                bf8 ak = *(const bf8*)swzc(ktc, nb*16 + lc, ks*4 + quad);
                acc[nb] = MFMA(ak, aq[ks], acc[nb]);
            }
        }
        // per-lane max via max3 tree (acc already includes mask)
        float m0_ = max3f(acc[0][0], acc[0][1], acc[0][2]);
        float m1_ = max3f(acc[0][3], acc[1][0], acc[1][1]);
        float m2_ = max3f(acc[1][2], acc[1][3], acc[2][0]);
        float m3_ = max3f(acc[2][1], acc[2][2], acc[2][3]);
        float m4_ = max3f(acc[3][0], acc[3][1], acc[3][2]);
        float mxl = fmaxf(max3f(m0_, m1_, m2_), max3f(m3_, m4_, acc[3][3]));
        // defer-max: only reduce/rescale when some lane grew past rm + 8
        if (__any(mxl > rm + 8.f)){
            float mx = fmaxf(mxl, __shfl_xor(mxl, 16, 64));
            mx = fmaxf(mx, __shfl_xor(mx, 32, 64));
            float nm = fmaxf(rm, mx);
            float fac = ex2(rm - nm);
            rm = nm;
            float f0 = __shfl(fac, quad*4+0, 64);
            float f1 = __shfl(fac, quad*4+1, 64);
            float f2 = __shfl(fac, quad*4+2, 64);
            float f3 = __shfl(fac, quad*4+3, 64);
            racc[0] *= f0; racc[1] *= f1; racc[2] *= f2; racc[3] *= f3;
            #pragma unroll
            for (int nb = 0; nb < 4; nb++){
                oacc[nb][0] *= f0; oacc[nb][1] *= f1;
                oacc[nb][2] *= f2; oacc[nb][3] *= f3;
            }
        }
        // P packed via cvt_pk straight into PV A-fragments; row sums on the
        // matrix pipe via the ones fragment.
        #pragma unroll
        for (int a1 = 0; a1 < 2; a1++){
            bfpack pk;
            pk.u[0] = cvtpk(ex2(acc[2*a1][0] - rm),   ex2(acc[2*a1][1] - rm));
            pk.u[1] = cvtpk(ex2(acc[2*a1][2] - rm),   ex2(acc[2*a1][3] - rm));
            pk.u[2] = cvtpk(ex2(acc[2*a1+1][0] - rm), ex2(acc[2*a1+1][1] - rm));
            pk.u[3] = cvtpk(ex2(acc[2*a1+1][2] - rm), ex2(acc[2*a1+1][3] - rm));
            bf8 ap = pk.v;
            racc = MFMA(ap, ones, racc);
            #pragma unroll
            for (int nb2 = 0; nb2 < 4; nb2++){
                bf8 bv = *(const bf8*)swzc(vtc, nb2*16 + lc, a1*4 + quad);
                oacc[nb2] = MFMA(ap, bv, oacc[nb2]);
            }
        }
        __syncthreads();   // one barrier/tile: drains shadow staging + ds_reads
        #pragma unroll
        for (int a1 = 0; a1 < 2; a1++)
            #pragma unroll
            for (int b1 = 0; b1 < 2; b1++)
                mv[a1][b1] = mvn[a1][b1];
        cur ^= 1;
    }
    // lstc = rm + log2(l)
    float rmr[4];
    #pragma unroll
    for (int r = 0; r < 4; r++) rmr[r] = __shfl(rm, quad*4 + r, 64);
    size_t sbase = ((size_t)(b*Hc+h))*Sc + qs0 + wv_*16;
    if (lc == 0){
        #pragma unroll
        for (int r = 0; r < 4; r++)
            lstc[sbase + quad*4 + r] = rmr[r] + log2f(racc[r]);
    }
    // ctx normalized by the full row-sum (racc rows match oacc rows)
    #pragma unroll
    for (int r = 0; r < 4; r++){
        float ir = 1.f/racc[r];
        int tok = qs0 + wv_*16 + quad*4 + r;
        #pragma unroll
        for (int nb = 0; nb < 4; nb++){
            int hd = nb*16 + lc;
            c0[((size_t)(b*Sc + tok))*Ec + h*HDc + hd] = f2b(oacc[nb][r]*ir);
        }
    }
}

// ---------------------------------------------------------------------------
// 8. attn_weights: q-tile 64, K-TILE 128 (halved h-loop staging/barrier
//    overhead per element), loop all 16 h. grid (32, 16, 2) = (q, k, b).
//    -lstc preloaded as the MFMA C-operand; Q pre-scaled by C2.
// ---------------------------------------------------------------------------
__global__ __launch_bounds__(256) void k_attnw(
    const u16* __restrict__ qb, const u16* __restrict__ kb,
    const u16* __restrict__ maskb, const float* __restrict__ lstc,
    float* __restrict__ awout)
{
    int qs0 = blockIdx.x*64, ks0 = blockIdx.y*128, b = blockIdx.z;
    int t = threadIdx.x, lane = t & 63, wv_ = t >> 6;
    int quad = lane >> 4, lc = lane & 15;
    __shared__ u16 kt[128*64];
    __shared__ float scc[64];
    f32x4 T[8];
    #pragma unroll
    for (int j=0;j<8;j++) T[j] = (f32x4){0.f,0.f,0.f,0.f};

    int lsub = lane >> 3;
    int colsw = ((lane & 7) ^ lsub) << 3;

    for (int h = 0; h < Hc; h++){
        __syncthreads();
        const u16* qp = qb + ((size_t)(b*Hc+h))*Sc*HDc;
        const u16* kp = kb + ((size_t)(b*Hc+h))*Sc*HDc;
        bf8 aq[2];
        #pragma unroll
        for (int ks = 0; ks < 2; ks++)
            aq[ks] = *(const bf8*)(qp + (size_t)(qs0 + wv_*16 + lc)*HDc + ks*32 + quad*8);
        #pragma unroll
        for (int i = 0; i < 4; i++){
            int lr = wv_*32 + i*8 + lsub;
            gl16(kp + (size_t)(ks0 + lr)*HDc + colsw, &kt[(wv_*32 + i*8)*64]);
        }
        if (t < 64)
            scc[t] = -lstc[((size_t)(b*Hc+h))*Sc + qs0 + t];   // negated
        __syncthreads();
        // C init = -lstc for this lane's 4 output rows (consecutive floats)
        f32x4 minit = *(const f32x4*)&scc[wv_*16 + quad*4];
        f32x4 acc[8];
        #pragma unroll
        for (int j=0;j<8;j++) acc[j] = minit;
        #pragma unroll
        for (int ks = 0; ks < 2; ks++){
            #pragma unroll
            for (int nb = 0; nb < 8; nb++){
                bf8 bb = *(const bf8*)swzc(kt, nb*16 + lc, ks*4 + quad);
                acc[nb] = MFMA(aq[ks], bb, acc[nb]);
            }
        }
        #pragma unroll
        for (int r = 0; r < 4; r++){
            #pragma unroll
            for (int nb = 0; nb < 8; nb++)
                T[nb][r] += ex2(acc[nb][r]);
        }
    }
    #pragma unroll
    for (int r = 0; r < 4; r++){
        int gq = qs0 + wv_*16 + quad*4 + r;
        #pragma unroll
        for (int nb = 0; nb < 8; nb++){
            int gk = ks0 + nb*16 + lc;
            float mk = b2f(maskb[(size_t)gq*Sc + gk]);   // mask*log2e
            awout[(size_t)b*Sc*Sc + (size_t)gq*Sc + gk]
                = T[nb][r]*ex2(mk)*(1.f/16.f);
        }
    }
}

// ---------------------------------------------------------------------------
// 10. output projection, MFMA. grid (8, NTILES). XOR-swizzled tiles staged
//     via global_load_lds (same mapping as k_qkv).
// ---------------------------------------------------------------------------
__global__ __launch_bounds__(256) void k_oproj(
    const u16* __restrict__ ctxb, const u16* __restrict__ woT,
    const int* __restrict__ perm, const int* __restrict__ tmeta,
    const u16* __restrict__ zbuf, float* __restrict__ opre)
{
    int meta = tmeta[blockIdx.y];
    if (meta < 0) return;
    int b = meta >> 1, m = meta & 1;
    const u16* W = woT + (size_t)m*Ec*Dc;
    int c0 = blockIdx.x*128;
    int t = threadIdx.x, lane = t & 63, wv_ = t >> 6;
    int quad = lane >> 4, lc = lane & 15;
    __shared__ u16 at[128*64];
    __shared__ u16 bt[128*64];
    __shared__ int sperm[128];
    if (t < 128) sperm[t] = perm[blockIdx.y*128 + t];
    f32x4 acc[2][8];
    #pragma unroll
    for (int i=0;i<2;i++)
        #pragma unroll
        for (int j=0;j<8;j++) acc[i][j] = (f32x4){0.f,0.f,0.f,0.f};
    __syncthreads();

    int colsw = ((lane & 7) ^ (lane >> 3)) << 3;
    const u16* ab[4]; const u16* bb[4];
    #pragma unroll
    for (int i = 0; i < 4; i++){
        int row = wv_*32 + i*8 + (lane >> 3);
        int s_ = sperm[row];
        ab[i] = (s_ >= 0) ? (ctxb + ((size_t)(b*Sc + s_))*Ec + colsw) : zbuf;
        bb[i] = W + (size_t)(c0 + row)*Ec + colsw;
    }

    for (int d0 = 0; d0 < Ec; d0 += 64){
        #pragma unroll
        for (int i = 0; i < 4; i++){
            gl16(ab[i] + d0, &at[(wv_*4 + i)*512]);
            gl16(bb[i] + d0, &bt[(wv_*4 + i)*512]);
        }
        __syncthreads();
        #pragma unroll
        for (int ks = 0; ks < 2; ks++){
            bf8 a0 = *(const bf8*)swzc(at, wv_*32 + lc,      ks*4 + quad);
            bf8 a1 = *(const bf8*)swzc(at, wv_*32 + 16 + lc, ks*4 + quad);
            #pragma unroll
            for (int nb = 0; nb < 8; nb++){
                bf8 bb2 = *(const bf8*)swzc(bt, nb*16 + lc, ks*4 + quad);
                acc[0][nb] = MFMA(a0, bb2, acc[0][nb]);
                acc[1][nb] = MFMA(a1, bb2, acc[1][nb]);
            }
        }
        __syncthreads();
    }
    #pragma unroll
    for (int mb = 0; mb < 2; mb++){
        #pragma unroll
        for (int r = 0; r < 4; r++){
            int row = wv_*32 + mb*16 + quad*4 + r;
            int s_ = sperm[row];
            if (s_ < 0) continue;
            #pragma unroll
            for (int nb = 0; nb < 8; nb++){
                int col = c0 + nb*16 + lc;
                opre[((size_t)(b*Sc + s_))*Dc + col] = acc[mb][nb][r];
            }
        }
    }
}

// ---------------------------------------------------------------------------
// 11. final RMSNorm over D -> out
// ---------------------------------------------------------------------------
__global__ __launch_bounds__(256) void k_onorm(
    const float* __restrict__ opre, const float* __restrict__ anw,
    const int* __restrict__ mod, float* __restrict__ out)
{
    int row = blockIdx.x;
    int m = mod[row];
    int t = threadIdx.x;
    float val[4];
    float ss = 0.f;
    #pragma unroll
    for (int j=0;j<4;j++){
        val[j] = opre[(size_t)row*Dc + t + 256*j];
        ss += val[j]*val[j];
    }
    #pragma unroll
    for (int o=32;o>0;o>>=1) ss += __shfl_xor(ss, o, 64);
    __shared__ float red[4];
    int wid = t>>6, lane = t&63;
    if (lane==0) red[wid]=ss;
    __syncthreads();
    float tot = red[0]+red[1]+red[2]+red[3];
    float rms = rsqrtf(tot*(1.f/1024.f) + EPSc);
    #pragma unroll
    for (int j=0;j<4;j++)
        out[(size_t)row*Dc + t + 256*j] = val[j]*rms*anw[m*Dc + t + 256*j];
}

// ---------------------------------------------------------------------------
extern "C" void kernel_launch(void* const* d_in, const int* in_sizes, int n_in,
                              void* d_out, int out_size, void* d_ws, size_t ws_size,
                              hipStream_t stream)
{
    const float* x    = (const float*)d_in[0];
    const float* mask = (const float*)d_in[1];
    const int*   mod  = (const int*)  d_in[2];
    const float* Wq   = (const float*)d_in[3];
    const float* Wk   = (const float*)d_in[4];
    const float* Wv   = (const float*)d_in[5];
    const float* Wo   = (const float*)d_in[6];
    const float* qnw  = (const float*)d_in[7];
    const float* knw  = (const float*)d_in[8];
    const float* anw  = (const float*)d_in[9];

    float* out   = (float*)d_out;                 // [B,S,D]
    float* awout = out + (size_t)Bc*Sc*Dc;        // [B,S,S]

    float* ws = (float*)d_ws;
    u16* qb    = (u16*)(ws + 0);
    u16* kb    = (u16*)(ws + 2097152);
    u16* vb    = (u16*)(ws + 4194304);   // dead after k_vt
    u16* xb    = (u16*)(ws + 6291456);   // dead after k_qkv -> ctx
    u16* ctx0  = xb;
    u16* vtb   = (u16*)(ws + 8388608);
    u16* wqT   = (u16*)(ws + 10485760);
    u16* wkT   = (u16*)(ws + 11534336);
    u16* wvT   = (u16*)(ws + 12582912);
    u16* woT   = (u16*)(ws + 13631488);
    float* lstc= ws + 14680064;          // rm + log2(l), 65536
    u16* maskb = (u16*)(ws + 15335424);  // mask*log2e, bf16
    int* perm  = (int*)(ws + 17432576);
    int* tmeta = perm + NTILES*TILE_R;
    u16* zbuf  = (u16*)(tmeta + NTILES + 28);   // 4KB zero scratch (aligned)
    float* opre = ws;                    // aliases qb+kb (dead by then)

    k_pre   <<<dim3(16385),        256, 0, stream>>>(x, mask, mod, Wq, Wk, Wv, Wo,
                                                     xb, maskb, wqT, wkT, wvT, woT,
                                                     perm, tmeta, zbuf);
    k_qkv   <<<dim3(8,NTILES,3),   256, 0, stream>>>(xb, wqT, wkT, wvT, perm, tmeta,
                                                     qnw, knw, zbuf, qb, kb, vb);
    k_vt    <<<dim3(32,32),        256, 0, stream>>>(vb, vtb);
    k_flash <<<dim3(32,16,2),      256, 0, stream>>>(qb, kb, vtb, maskb, lstc, ctx0);
    k_attnw <<<dim3(32,16,2),      256, 0, stream>>>(qb, kb, maskb, lstc, awout);
    k_oproj <<<dim3(8,NTILES),     256, 0, stream>>>(ctx0, woT, perm, tmeta, zbuf, opre);
    k_onorm <<<dim3(4096),         256, 0, stream>>>(opre, anw, mod, out);
}